// Round 3
// baseline (1875.014 us; speedup 1.0000x reference)
//
#include <hip/hip_runtime.h>
#include <hip/hip_bf16.h>
#include <cstdint>
#include <cstddef>

typedef __hip_bfloat16 bf16;

// ---- problem constants ----
#define B_   2
#define L_   4096
#define DM_  768      // d_model
#define DI_  1536     // d_inner
#define NH_  24       // nheads
#define HD_  64       // headdim
#define DS_  64       // d_state
#define CH_  256      // chunk
#define NC_  16       // n chunks
#define CD_  1664     // conv dim
#define DIP_ 3248     // d_in_proj
#define EPS_ 1e-5f

#define ROWS_ (B_*L_)        // 8192
#define BB4_  (2*B_)         // 4 ssd batches

__device__ __forceinline__ float b2f(bf16 v) { return __bfloat162float(v); }
__device__ __forceinline__ bf16  f2b(float v) { return __float2bfloat16(v); }

// ------------------------------------------------------------------
// LayerNorm: one block per row (768 elems), 256 threads
// ------------------------------------------------------------------
__global__ __launch_bounds__(256) void ln_kernel(const float* __restrict__ x,
                                                 const float* __restrict__ w,
                                                 const float* __restrict__ bb,
                                                 float* __restrict__ u) {
    int row = blockIdx.x, tid = threadIdx.x;
    const float* xr = x + (size_t)row * DM_;
    float v0 = xr[tid], v1 = xr[tid + 256], v2 = xr[tid + 512];
    float s = v0 + v1 + v2;
    float q = v0*v0 + v1*v1 + v2*v2;
    for (int off = 32; off > 0; off >>= 1) {
        s += __shfl_down(s, off);
        q += __shfl_down(q, off);
    }
    __shared__ float rs[4], rq[4];
    __shared__ float mean_s, rstd_s;
    int lane = tid & 63, wid = tid >> 6;
    if (!lane) { rs[wid] = s; rq[wid] = q; }
    __syncthreads();
    if (!tid) {
        float S = rs[0]+rs[1]+rs[2]+rs[3];
        float Q = rq[0]+rq[1]+rq[2]+rq[3];
        float mu = S / (float)DM_;
        float var = Q / (float)DM_ - mu*mu;
        mean_s = mu; rstd_s = rsqrtf(var + EPS_);
    }
    __syncthreads();
    float mu = mean_s, rstd = rstd_s;
    float* ur = u + (size_t)row * DM_;
    ur[tid]       = (v0 - mu) * rstd * w[tid]       + bb[tid];
    ur[tid + 256] = (v1 - mu) * rstd * w[tid + 256] + bb[tid + 256];
    ur[tid + 512] = (v2 - mu) * rstd * w[tid + 512] + bb[tid + 512];
}

// ------------------------------------------------------------------
// in_proj GEMM, f32 A/W, split bf16/f32 outputs:
//   cols [0,1536)      -> zbuf (bf16) [row*1536 + n]
//   cols [1536,3200)   -> xbc  (bf16) [row*1664 + n-1536]
//   cols [3200,3248)   -> dtr  (f32)  [row*48   + n-3200]
// ------------------------------------------------------------------
__global__ __launch_bounds__(256) void gemm_inproj(const float* __restrict__ A,
                                                   const float* __restrict__ W,
                                                   bf16* __restrict__ zbuf,
                                                   bf16* __restrict__ xbc,
                                                   float* __restrict__ dtr) {
    __shared__ float As[16][65];
    __shared__ float Ws[16][65];
    int tid = threadIdx.x;
    int tx = tid & 15, ty = tid >> 4;
    int bm = blockIdx.y * 64, bn = blockIdx.x * 64;
    float acc[4][4] = {};
    int kk = tid & 15;
    int r0 = tid >> 4;
    const int K = DM_;
    for (int k0 = 0; k0 < K; k0 += 16) {
        #pragma unroll
        for (int rr = 0; rr < 4; rr++) {
            int r = r0 + rr * 16;
            As[kk][r] = A[(size_t)(bm + r) * K + k0 + kk];
            int n = bn + r;
            Ws[kk][r] = (n < DIP_) ? W[(size_t)n * K + k0 + kk] : 0.f;
        }
        __syncthreads();
        #pragma unroll
        for (int k = 0; k < 16; k++) {
            float a[4], b[4];
            #pragma unroll
            for (int i = 0; i < 4; i++) a[i] = As[k][i*16 + ty];
            #pragma unroll
            for (int j = 0; j < 4; j++) b[j] = Ws[k][j*16 + tx];
            #pragma unroll
            for (int i = 0; i < 4; i++)
                #pragma unroll
                for (int j = 0; j < 4; j++)
                    acc[i][j] += a[i] * b[j];
        }
        __syncthreads();
    }
    #pragma unroll
    for (int i = 0; i < 4; i++) {
        int m = bm + i*16 + ty;
        #pragma unroll
        for (int j = 0; j < 4; j++) {
            int n = bn + j*16 + tx;
            float v = acc[i][j];
            if (n < DI_)            zbuf[(size_t)m * DI_ + n] = f2b(v);
            else if (n < DI_ + CD_) xbc[(size_t)m * CD_ + (n - DI_)] = f2b(v);
            else if (n < DIP_)      dtr[(size_t)m * 48 + (n - DI_ - CD_)] = v;
        }
    }
}

// ------------------------------------------------------------------
// out_proj GEMM: A bf16 [M,K], W f32 [N,K], + resid f32, C f32.
// ------------------------------------------------------------------
__global__ __launch_bounds__(256) void gemm_out(const bf16* __restrict__ A,
                                                const float* __restrict__ W,
                                                const float* __restrict__ resid,
                                                float* __restrict__ C,
                                                int M, int N, int K) {
    __shared__ float As[16][65];
    __shared__ float Ws[16][65];
    int tid = threadIdx.x;
    int tx = tid & 15, ty = tid >> 4;
    int bm = blockIdx.y * 64, bn = blockIdx.x * 64;
    float acc[4][4] = {};
    int kk = tid & 15;
    int r0 = tid >> 4;
    for (int k0 = 0; k0 < K; k0 += 16) {
        #pragma unroll
        for (int rr = 0; rr < 4; rr++) {
            int r = r0 + rr * 16;
            As[kk][r] = b2f(A[(size_t)(bm + r) * K + k0 + kk]);
            int n = bn + r;
            Ws[kk][r] = (n < N) ? W[(size_t)n * K + k0 + kk] : 0.f;
        }
        __syncthreads();
        #pragma unroll
        for (int k = 0; k < 16; k++) {
            float a[4], b[4];
            #pragma unroll
            for (int i = 0; i < 4; i++) a[i] = As[k][i*16 + ty];
            #pragma unroll
            for (int j = 0; j < 4; j++) b[j] = Ws[k][j*16 + tx];
            #pragma unroll
            for (int i = 0; i < 4; i++)
                #pragma unroll
                for (int j = 0; j < 4; j++)
                    acc[i][j] += a[i] * b[j];
        }
        __syncthreads();
    }
    #pragma unroll
    for (int i = 0; i < 4; i++) {
        int m = bm + i*16 + ty;
        #pragma unroll
        for (int j = 0; j < 4; j++) {
            int n = bn + j*16 + tx;
            if (n < N)
                C[(size_t)m * N + n] = acc[i][j] + resid[(size_t)m * N + n];
        }
    }
}

// ------------------------------------------------------------------
// Depthwise causal conv7 + SiLU on xbc [8192, 1664] (bf16 -> bf16).
// ------------------------------------------------------------------
__global__ __launch_bounds__(256) void conv_kernel(const bf16* __restrict__ xbc,
                                                   const float* __restrict__ cw,
                                                   const float* __restrict__ cb,
                                                   bf16* __restrict__ out) {
    size_t idx = (size_t)blockIdx.x * 256 + threadIdx.x;
    if (idx >= (size_t)ROWS_ * CD_) return;
    int c = idx % CD_;
    int t = (idx / CD_) % L_;
    int b = idx / ((size_t)CD_ * L_);
    float acc = cb[c];
    #pragma unroll
    for (int j = 0; j < 7; j++) {
        int tt = t - 6 + j;
        if (tt >= 0)
            acc += b2f(xbc[((size_t)(b * L_ + tt)) * CD_ + c]) * cw[c * 7 + j];
    }
    acc = acc / (1.f + __expf(-acc));   // silu
    out[idx] = f2b(acc);
}

// ------------------------------------------------------------------
// dt: softplus(dt2 + bias), with time-flip for backward batches.
// dt4 layout: [(bb*L + t)*NH + h]
// ------------------------------------------------------------------
__global__ __launch_bounds__(256) void dt_kernel(const float* __restrict__ dtr,
                                                 const float* __restrict__ dt_bias,
                                                 float* __restrict__ dt4) {
    int idx = blockIdx.x * 256 + threadIdx.x;
    if (idx >= BB4_ * L_ * NH_) return;
    int h = idx % NH_;
    int t = (idx / NH_) % L_;
    int bbx = idx / (NH_ * L_);
    int bp = bbx & 1;
    float raw;
    if (bbx < 2) raw = dtr[((size_t)(bp * L_ + t)) * 48 + h];
    else         raw = dtr[((size_t)(bp * L_ + (L_ - 1 - t))) * 48 + NH_ + h];
    float v = raw + dt_bias[h];
    float dt = (v > 20.f) ? v : log1pf(__expf(v));
    dt4[idx] = dt;
}

// ------------------------------------------------------------------
// per-chunk inclusive cumsum of dt*A.  Acum layout: [((bb*NH+h)*NC+c)*CH + l]
// ------------------------------------------------------------------
__global__ __launch_bounds__(256) void scan_kernel(const float* __restrict__ dt4,
                                                   const float* __restrict__ A_log,
                                                   float* __restrict__ Acum) {
    int bid = blockIdx.x;          // ((bb*NH+h)*NC+c)
    int c  = bid % NC_;
    int h  = (bid / NC_) % NH_;
    int bbx = bid / (NC_ * NH_);
    int l = threadIdx.x;
    float Ah = -__expf(A_log[h]);
    float val = dt4[((size_t)(bbx * L_) + c * CH_ + l) * NH_ + h] * Ah;
    __shared__ float sc[256];
    sc[l] = val; __syncthreads();
    for (int off = 1; off < 256; off <<= 1) {
        float t = (l >= off) ? sc[l - off] : 0.f;
        __syncthreads();
        sc[l] += t;
        __syncthreads();
    }
    Acum[(size_t)bid * CH_ + l] = sc[l];
}

// ------------------------------------------------------------------
// chunk states: S[n,p] = sum_l B[l,n]*exp(Atot-Acum[l])*X[l,p]
// states layout: [((bb*NC+c)*NH+h)*64*64 + n*64 + p]  (bf16)
// ------------------------------------------------------------------
__global__ __launch_bounds__(256) void states_kernel(const bf16* __restrict__ conv,
                                                     const float* __restrict__ dt4,
                                                     const float* __restrict__ Acum,
                                                     bf16* __restrict__ states) {
    int bid = blockIdx.x;          // (bb*NC+c)*NH + h
    int h = bid % NH_;
    int c = (bid / NH_) % NC_;
    int bbx = bid / (NH_ * NC_);
    int bp = bbx & 1;
    bool flip = bbx >= 2;
    int tid = threadIdx.x;
    int tx = tid & 15, ty = tid >> 4;
    size_t abase = ((size_t)(bbx * NH_ + h) * NC_ + c) * CH_;
    float Atot = Acum[abase + CH_ - 1];
    __shared__ float Bs[64][65];
    __shared__ float Xs[64][65];
    float acc[4][4] = {};
    for (int lt = 0; lt < 4; lt++) {
        for (int rr = 0; rr < 16; rr++) {
            int li = tid + rr * 256;
            int lr = li >> 6, col = li & 63;
            int l = lt * 64 + lr;
            int t = c * CH_ + l;
            int tt = flip ? (L_ - 1 - t) : t;
            size_t ro = ((size_t)(bp * L_ + tt)) * CD_;
            float decay = __expf(Atot - Acum[abase + l]);
            Bs[lr][col] = b2f(conv[ro + DI_ + col]) * decay;
            Xs[lr][col] = b2f(conv[ro + h * HD_ + col]) * dt4[((size_t)(bbx * L_) + t) * NH_ + h];
        }
        __syncthreads();
        for (int l = 0; l < 64; l++) {
            float bv[4], xv[4];
            #pragma unroll
            for (int i = 0; i < 4; i++) bv[i] = Bs[l][i*16 + ty];
            #pragma unroll
            for (int j = 0; j < 4; j++) xv[j] = Xs[l][j*16 + tx];
            #pragma unroll
            for (int i = 0; i < 4; i++)
                #pragma unroll
                for (int j = 0; j < 4; j++)
                    acc[i][j] += bv[i] * xv[j];
        }
        __syncthreads();
    }
    size_t sbase = (size_t)bid * 64 * 64;
    #pragma unroll
    for (int i = 0; i < 4; i++)
        #pragma unroll
        for (int j = 0; j < 4; j++)
            states[sbase + (size_t)(i*16 + ty) * 64 + (j*16 + tx)] = f2b(acc[i][j]);
}

// ------------------------------------------------------------------
// inter-chunk recurrence: prev[c] = prev[c-1]*exp(T_{c-1}) + S_{c-1}
// ------------------------------------------------------------------
__global__ __launch_bounds__(256) void chunkscan_kernel(const bf16* __restrict__ states,
                                                        const float* __restrict__ Acum,
                                                        bf16* __restrict__ prev) {
    int bid = blockIdx.x;  // bb*NH + h
    int h = bid % NH_;
    int bbx = bid / NH_;
    int tid = threadIdx.x;
    float run[16];
    #pragma unroll
    for (int k = 0; k < 16; k++) run[k] = 0.f;
    for (int c = 0; c < NC_; c++) {
        float Tc = Acum[((size_t)(bbx * NH_ + h) * NC_ + c) * CH_ + CH_ - 1];
        float ec = __expf(Tc);
        size_t base = ((size_t)(bbx * NC_ + c) * NH_ + h) * 4096;
        #pragma unroll
        for (int k = 0; k < 16; k++) {
            size_t e = tid + k * 256;
            prev[base + e] = f2b(run[k]);
            run[k] = run[k] * ec + b2f(states[base + e]);
        }
    }
}

// ------------------------------------------------------------------
// Y = Y_diag + Y_off per (b,c,h,l-tile of 64).
// pass 0: forward batches (bbx = b), write yc[b, t+1] = y   (t==L-1 -> zero row 0)
// pass 1: backward batches (bbx = b+2), yc[b, L-2-t] += y   (t==L-1 dropped)
// ------------------------------------------------------------------
__global__ __launch_bounds__(256) void ydiag_kernel(const bf16* __restrict__ conv,
                                                    const float* __restrict__ dt4,
                                                    const float* __restrict__ Acum,
                                                    const bf16* __restrict__ prev,
                                                    bf16* __restrict__ yc,
                                                    int pass) {
    int bid = blockIdx.x;   // ((b*NC+c)*NH+h)*4 + lt   (b in 0..1)
    int lt = bid & 3;
    int q  = bid >> 2;
    int h  = q % NH_;
    int r  = q / NH_;
    int c  = r % NC_;
    int b  = r / NC_;
    int bbx = pass ? (b + 2) : b;
    int bp = b;
    bool flip = pass != 0;
    int tid = threadIdx.x;
    int tx = tid & 15, ty = tid >> 4;
    size_t abase = ((size_t)(bbx * NH_ + h) * NC_ + c) * CH_;

    __shared__ float Cs[64][65];
    __shared__ float Bs[64][65];   // prev / B tile, then reused for G
    __shared__ float Xs[64][65];
    __shared__ float aL[64], aS[64];

    // load C tile (rows lt*64..) and prev tile (into Bs), aL
    for (int rr = 0; rr < 16; rr++) {
        int li = tid + rr * 256;
        int lr = li >> 6, col = li & 63;
        int l = lt * 64 + lr;
        int t = c * CH_ + l;
        int tt = flip ? (L_ - 1 - t) : t;
        Cs[lr][col] = b2f(conv[((size_t)(bp * L_ + tt)) * CD_ + DI_ + DS_ + col]);
    }
    {
        size_t pbase = ((size_t)(bbx * NC_ + c) * NH_ + h) * 4096;
        for (int rr = 0; rr < 16; rr++) {
            int li = tid + rr * 256;
            Bs[li >> 6][li & 63] = b2f(prev[pbase + li]);
        }
    }
    if (tid < 64) aL[tid] = Acum[abase + lt * 64 + tid];
    __syncthreads();

    float acc[4][4] = {};
    // Y_off = (Cs @ prev) * exp(aL[l])
    for (int n = 0; n < 64; n++) {
        float cv[4], pv[4];
        #pragma unroll
        for (int i = 0; i < 4; i++) cv[i] = Cs[i*16 + ty][n];
        #pragma unroll
        for (int j = 0; j < 4; j++) pv[j] = Bs[n][j*16 + tx];
        #pragma unroll
        for (int i = 0; i < 4; i++)
            #pragma unroll
            for (int j = 0; j < 4; j++)
                acc[i][j] += cv[i] * pv[j];
    }
    #pragma unroll
    for (int i = 0; i < 4; i++) {
        float e = __expf(aL[i*16 + ty]);
        #pragma unroll
        for (int j = 0; j < 4; j++) acc[i][j] *= e;
    }
    __syncthreads();

    // diagonal-block contributions
    for (int st = 0; st <= lt; st++) {
        for (int rr = 0; rr < 16; rr++) {
            int li = tid + rr * 256;
            int sr = li >> 6, col = li & 63;
            int s = st * 64 + sr;
            int t = c * CH_ + s;
            int tt = flip ? (L_ - 1 - t) : t;
            size_t ro = ((size_t)(bp * L_ + tt)) * CD_;
            Bs[sr][col] = b2f(conv[ro + DI_ + col]);
            Xs[sr][col] = b2f(conv[ro + h * HD_ + col]) * dt4[((size_t)(bbx * L_) + t) * NH_ + h];
        }
        if (tid < 64) aS[tid] = Acum[abase + st * 64 + tid];
        __syncthreads();
        // G = (C B^T) in registers
        float gacc[4][4] = {};
        for (int n = 0; n < 64; n++) {
            float cv[4], bv[4];
            #pragma unroll
            for (int i = 0; i < 4; i++) cv[i] = Cs[i*16 + ty][n];
            #pragma unroll
            for (int j = 0; j < 4; j++) bv[j] = Bs[j*16 + tx][n];
            #pragma unroll
            for (int i = 0; i < 4; i++)
                #pragma unroll
                for (int j = 0; j < 4; j++)
                    gacc[i][j] += cv[i] * bv[j];
        }
        __syncthreads();   // all reads of Bs (B tile) done
        // overwrite Bs with masked decayed G[l][s]
        #pragma unroll
        for (int i = 0; i < 4; i++) {
            int l = i*16 + ty;
            #pragma unroll
            for (int j = 0; j < 4; j++) {
                int s = j*16 + tx;
                bool valid = (st < lt) || (l >= s);
                Bs[l][s] = valid ? gacc[i][j] * __expf(aL[l] - aS[s]) : 0.f;
            }
        }
        __syncthreads();
        // acc += G @ Xs
        for (int s = 0; s < 64; s++) {
            float gv[4], xv[4];
            #pragma unroll
            for (int i = 0; i < 4; i++) gv[i] = Bs[i*16 + ty][s];
            #pragma unroll
            for (int j = 0; j < 4; j++) xv[j] = Xs[s][j*16 + tx];
            #pragma unroll
            for (int i = 0; i < 4; i++)
                #pragma unroll
                for (int j = 0; j < 4; j++)
                    acc[i][j] += gv[i] * xv[j];
        }
        __syncthreads();
    }

    // fused roll/flip/add epilogue
    #pragma unroll
    for (int i = 0; i < 4; i++) {
        int l = i*16 + ty;
        int t = c * CH_ + lt * 64 + l;
        #pragma unroll
        for (int j = 0; j < 4; j++) {
            int p = j*16 + tx;
            float v = acc[i][j];
            if (!pass) {
                int pos = t + 1;
                if (pos == L_)
                    yc[((size_t)(b * L_) + 0) * DI_ + h * HD_ + p] = f2b(0.f);
                else
                    yc[((size_t)(b * L_) + pos) * DI_ + h * HD_ + p] = f2b(v);
            } else {
                int pos = L_ - 2 - t;
                if (pos >= 0) {
                    size_t o = ((size_t)(b * L_) + pos) * DI_ + h * HD_ + p;
                    yc[o] = f2b(b2f(yc[o]) + v);
                }
            }
        }
    }
}

// ------------------------------------------------------------------
// combine: D-term GEMV, silu(z) gate, RMSNorm
// ------------------------------------------------------------------
__global__ __launch_bounds__(256) void combine_kernel(const bf16* __restrict__ yc,
                                                      const bf16* __restrict__ conv,
                                                      const bf16* __restrict__ zbuf,
                                                      const float* __restrict__ fcD,
                                                      const float* __restrict__ Dvec,
                                                      const float* __restrict__ rms_w,
                                                      bf16* __restrict__ ybuf) {
    int row = blockIdx.x;   // b*L + t
    int tid = threadIdx.x;
    __shared__ float xog_s[DI_];
    __shared__ float dterm_s[NH_];
    __shared__ float rs[4];
    __shared__ float scale_s;
    float yv[6], xog[6], zv[6];
    const bf16* convrow = conv + (size_t)row * CD_;
    const bf16* zrow = zbuf + (size_t)row * DI_;
    const bf16* ycrow = yc + (size_t)row * DI_;
    #pragma unroll
    for (int k = 0; k < 6; k++) {
        int d = tid + k * 256;
        float xo = b2f(convrow[d]);
        xog[k] = xo; xog_s[d] = xo;
        zv[k] = b2f(zrow[d]);
        yv[k] = b2f(ycrow[d]);
    }
    __syncthreads();
    // D-term: 4 waves x 6 heads, 1536-long dots
    int wid = tid >> 6, lane = tid & 63;
    for (int hh = 0; hh < 6; hh++) {
        int h = wid * 6 + hh;
        float s = 0.f;
        #pragma unroll
        for (int k = 0; k < 24; k++) {
            int d = lane + k * 64;
            s += xog_s[d] * fcD[(size_t)h * DI_ + d];
        }
        for (int off = 32; off > 0; off >>= 1) s += __shfl_down(s, off);
        if (!lane) dterm_s[h] = s + Dvec[h];
    }
    __syncthreads();
    float ss = 0.f;
    #pragma unroll
    for (int k = 0; k < 6; k++) {
        int d = tid + k * 256;
        int h = d >> 6;
        float y = yv[k] + xog[k] * dterm_s[h];
        float z = zv[k];
        y *= z / (1.f + __expf(-z));
        yv[k] = y;
        ss += y * y;
    }
    for (int off = 32; off > 0; off >>= 1) ss += __shfl_down(ss, off);
    if (!lane) rs[wid] = ss;
    __syncthreads();
    if (!tid) scale_s = rsqrtf((rs[0]+rs[1]+rs[2]+rs[3]) / (float)DI_ + EPS_);
    __syncthreads();
    float sc = scale_s;
    bf16* yrow = ybuf + (size_t)row * DI_;
    #pragma unroll
    for (int k = 0; k < 6; k++) {
        int d = tid + k * 256;
        yrow[d] = f2b(yv[k] * sc * rms_w[d]);
    }
}

// ------------------------------------------------------------------
extern "C" void kernel_launch(void* const* d_in, const int* in_sizes, int n_in,
                              void* d_out, int out_size, void* d_ws, size_t ws_size,
                              hipStream_t stream) {
    const float* x        = (const float*)d_in[0];
    const float* ln_w     = (const float*)d_in[1];
    const float* ln_b     = (const float*)d_in[2];
    const float* in_proj  = (const float*)d_in[3];
    const float* conv_w   = (const float*)d_in[4];
    const float* conv_b   = (const float*)d_in[5];
    const float* dt_bias  = (const float*)d_in[6];
    const float* A_log    = (const float*)d_in[7];
    const float* Dvec     = (const float*)d_in[8];
    const float* fc_D_w   = (const float*)d_in[9];
    const float* rms_w    = (const float*)d_in[10];
    const float* out_proj = (const float*)d_in[11];
    float* out = (float*)d_out;

    // ---- workspace layout (lifetime-aliased), ~110 MB total ----
    uint8_t* base = (uint8_t*)d_ws;
    size_t off = 0;
    auto alloc = [&](size_t bytes) -> void* {
        void* p = base + off;
        off += (bytes + 255) & ~(size_t)255;
        return p;
    };
    bf16*  buf_z    = (bf16*) alloc((size_t)ROWS_ * DI_ * 2);            // 25.2 MB [2..9]
    uint8_t* regA   = (uint8_t*)alloc((size_t)ROWS_ * CD_ * 2);          // 27.3 MB xbc[2..3]/st+prev[6..8]/y[9..10]
    float* buf_dtr  = (float*)alloc((size_t)ROWS_ * 48 * 4);             // 1.6 MB  [2..4]
    bf16*  buf_conv = (bf16*) alloc((size_t)ROWS_ * CD_ * 2);            // 27.3 MB [3..9]
    float* buf_dt   = (float*)alloc((size_t)BB4_ * L_ * NH_ * 4);        // 1.6 MB
    float* buf_acum = (float*)alloc((size_t)BB4_ * NH_ * NC_ * CH_ * 4); // 1.6 MB
    uint8_t* regB   = (uint8_t*)alloc((size_t)ROWS_ * DM_ * 4);          // 25.2 MB u[1..2]/yc[8..9]

    bf16*  buf_xbc  = (bf16*)regA;
    bf16*  buf_st   = (bf16*)regA;                                   // 12.6 MB
    bf16*  buf_prev = buf_st + (size_t)BB4_ * NC_ * NH_ * 4096;      // 12.6 MB
    bf16*  buf_y    = (bf16*)regA;
    float* buf_u    = (float*)regB;
    bf16*  buf_yc   = (bf16*)regB;

    // 1. LayerNorm
    ln_kernel<<<ROWS_, 256, 0, stream>>>(x, ln_w, ln_b, buf_u);
    // 2. in_proj GEMM with split outputs
    gemm_inproj<<<dim3((DIP_ + 63) / 64, ROWS_ / 64), 256, 0, stream>>>(
        buf_u, in_proj, buf_z, buf_xbc, buf_dtr);
    // 3. conv + silu
    {
        size_t tot = (size_t)ROWS_ * CD_;
        conv_kernel<<<(tot + 255) / 256, 256, 0, stream>>>(buf_xbc, conv_w, conv_b, buf_conv);
    }
    // 4. dt
    dt_kernel<<<(BB4_ * L_ * NH_) / 256, 256, 0, stream>>>(buf_dtr, dt_bias, buf_dt);
    // 5. per-chunk cumsum of dt*A
    scan_kernel<<<BB4_ * NH_ * NC_, 256, 0, stream>>>(buf_dt, A_log, buf_acum);
    // 6. chunk states  (writes into old xbc region — xbc dead after step 3)
    states_kernel<<<BB4_ * NC_ * NH_, 256, 0, stream>>>(buf_conv, buf_dt, buf_acum, buf_st);
    // 7. inter-chunk scan
    chunkscan_kernel<<<BB4_ * NH_, 256, 0, stream>>>(buf_st, buf_acum, buf_prev);
    // 8. Y = diag + off, fused roll/flip/add (two ordered passes)
    ydiag_kernel<<<B_ * NC_ * NH_ * 4, 256, 0, stream>>>(buf_conv, buf_dt, buf_acum, buf_prev, buf_yc, 0);
    ydiag_kernel<<<B_ * NC_ * NH_ * 4, 256, 0, stream>>>(buf_conv, buf_dt, buf_acum, buf_prev, buf_yc, 1);
    // 9. combine + D-term + gate + RMSNorm  (writes y into old st/prev region)
    combine_kernel<<<ROWS_, 256, 0, stream>>>(buf_yc, buf_conv, buf_z, fc_D_w, Dvec, rms_w, buf_y);
    // 10. out_proj GEMM + residual
    gemm_out<<<dim3((DM_ + 63) / 64, ROWS_ / 64), 256, 0, stream>>>(
        buf_y, out_proj, x, out, ROWS_, DM_, DI_);
}

// Round 4
// 977.256 us; speedup vs baseline: 1.9187x; 1.9187x over previous
//
#include <hip/hip_runtime.h>
#include <hip/hip_bf16.h>
#include <cstdint>
#include <cstddef>

typedef __hip_bfloat16 bf16;
typedef __attribute__((ext_vector_type(8))) short short8;
typedef __attribute__((ext_vector_type(4))) float f32x4;

// ---- problem constants ----
#define B_   2
#define L_   4096
#define DM_  768      // d_model
#define DI_  1536     // d_inner
#define NH_  24       // nheads
#define HD_  64       // headdim
#define DS_  64       // d_state
#define CH_  256      // chunk
#define NC_  16       // n chunks
#define CD_  1664     // conv dim
#define DIP_ 3248     // d_in_proj
#define EPS_ 1e-5f

#define ROWS_ (B_*L_)        // 8192
#define BB4_  (2*B_)         // 4 ssd batches

#define LDSK 40              // padded LDS row stride (bf16 elems) for MFMA tiles

__device__ __forceinline__ float b2f(bf16 v) { return __bfloat162float(v); }
__device__ __forceinline__ bf16  f2b(float v) { return __float2bfloat16(v); }

// ------------------------------------------------------------------
// cast f32 -> bf16 (for weights), 4 elems/thread
// ------------------------------------------------------------------
__global__ __launch_bounds__(256) void cast_f2b(const float* __restrict__ s,
                                                bf16* __restrict__ d, int n) {
    int i = (blockIdx.x * 256 + threadIdx.x) * 4;
    if (i + 3 < n) {
        float4 v = *(const float4*)(s + i);
        d[i]   = f2b(v.x); d[i+1] = f2b(v.y);
        d[i+2] = f2b(v.z); d[i+3] = f2b(v.w);
    } else {
        for (int k = i; k < n; k++) d[k] = f2b(s[k]);
    }
}

// ------------------------------------------------------------------
// LayerNorm: one block per row (768 elems), 256 threads. bf16 output.
// ------------------------------------------------------------------
__global__ __launch_bounds__(256) void ln_kernel(const float* __restrict__ x,
                                                 const float* __restrict__ w,
                                                 const float* __restrict__ bb,
                                                 bf16* __restrict__ u) {
    int row = blockIdx.x, tid = threadIdx.x;
    const float* xr = x + (size_t)row * DM_;
    float v0 = xr[tid], v1 = xr[tid + 256], v2 = xr[tid + 512];
    float s = v0 + v1 + v2;
    float q = v0*v0 + v1*v1 + v2*v2;
    for (int off = 32; off > 0; off >>= 1) {
        s += __shfl_down(s, off);
        q += __shfl_down(q, off);
    }
    __shared__ float rs[4], rq[4];
    __shared__ float mean_s, rstd_s;
    int lane = tid & 63, wid = tid >> 6;
    if (!lane) { rs[wid] = s; rq[wid] = q; }
    __syncthreads();
    if (!tid) {
        float S = rs[0]+rs[1]+rs[2]+rs[3];
        float Q = rq[0]+rq[1]+rq[2]+rq[3];
        float mu = S / (float)DM_;
        float var = Q / (float)DM_ - mu*mu;
        mean_s = mu; rstd_s = rsqrtf(var + EPS_);
    }
    __syncthreads();
    float mu = mean_s, rstd = rstd_s;
    bf16* ur = u + (size_t)row * DM_;
    ur[tid]       = f2b((v0 - mu) * rstd * w[tid]       + bb[tid]);
    ur[tid + 256] = f2b((v1 - mu) * rstd * w[tid + 256] + bb[tid + 256]);
    ur[tid + 512] = f2b((v2 - mu) * rstd * w[tid + 512] + bb[tid + 512]);
}

// ------------------------------------------------------------------
// MFMA bf16 GEMM (in_proj): C[8192,3248] = u[8192,768] @ W[3248,768]^T
// 128x128 tile, 4 waves (2x2), each wave 64x64 = 4x4 x (16x16x32 MFMA).
// Split epilogue: z (bf16), xbc (bf16), dtr (f32).
// ------------------------------------------------------------------
__global__ __launch_bounds__(256) void gemm_bf16_inproj(const bf16* __restrict__ A,
                                                        const bf16* __restrict__ W,
                                                        bf16* __restrict__ zbuf,
                                                        bf16* __restrict__ xbc,
                                                        float* __restrict__ dtr) {
    __shared__ short As[128 * LDSK];
    __shared__ short Ws[128 * LDSK];
    int tid = threadIdx.x;
    int wave = tid >> 6, lane = tid & 63;
    int wm = (wave >> 1) * 64, wn = (wave & 1) * 64;
    int bm = blockIdx.y * 128, bn = blockIdx.x * 128;
    f32x4 acc[4][4] = {};
    int lr = tid >> 1;            // 0..127 (tile row for staging)
    int lseg = (tid & 1) * 16;    // k sub-segment
    const int K = DM_;
    int fr = lane & 15, kg = (lane >> 4) * 8;
    for (int k0 = 0; k0 < K; k0 += 32) {
        const short* ag = (const short*)A + (size_t)(bm + lr) * K + k0 + lseg;
        short8 av0 = *(const short8*)ag;
        short8 av1 = *(const short8*)(ag + 8);
        short8 wv0 = {}, wv1 = {};
        int n = bn + lr;
        if (n < DIP_) {
            const short* wg = (const short*)W + (size_t)n * K + k0 + lseg;
            wv0 = *(const short8*)wg;
            wv1 = *(const short8*)(wg + 8);
        }
        __syncthreads();
        *(short8*)&As[lr*LDSK + lseg]     = av0;
        *(short8*)&As[lr*LDSK + lseg + 8] = av1;
        *(short8*)&Ws[lr*LDSK + lseg]     = wv0;
        *(short8*)&Ws[lr*LDSK + lseg + 8] = wv1;
        __syncthreads();
        short8 af[4], wf[4];
        #pragma unroll
        for (int i = 0; i < 4; i++)
            af[i] = *(const short8*)&As[(wm + i*16 + fr)*LDSK + kg];
        #pragma unroll
        for (int j = 0; j < 4; j++)
            wf[j] = *(const short8*)&Ws[(wn + j*16 + fr)*LDSK + kg];
        #pragma unroll
        for (int i = 0; i < 4; i++)
            #pragma unroll
            for (int j = 0; j < 4; j++)
                acc[i][j] = __builtin_amdgcn_mfma_f32_16x16x32_bf16(af[i], wf[j], acc[i][j], 0, 0, 0);
    }
    int rg = (lane >> 4) * 4;
    #pragma unroll
    for (int i = 0; i < 4; i++) {
        int mrow = bm + wm + i*16 + rg;
        #pragma unroll
        for (int j = 0; j < 4; j++) {
            int ncol = bn + wn + j*16 + fr;
            #pragma unroll
            for (int r = 0; r < 4; r++) {
                float v = acc[i][j][r];
                int m = mrow + r;
                if (ncol < DI_)            zbuf[(size_t)m * DI_ + ncol] = f2b(v);
                else if (ncol < DI_ + CD_) xbc[(size_t)m * CD_ + (ncol - DI_)] = f2b(v);
                else if (ncol < DIP_)      dtr[(size_t)m * 48 + (ncol - DI_ - CD_)] = v;
            }
        }
    }
}

// ------------------------------------------------------------------
// MFMA bf16 GEMM (out_proj): out[8192,768] = y[8192,1536] @ W[768,1536]^T + x
// ------------------------------------------------------------------
__global__ __launch_bounds__(256) void gemm_bf16_out(const bf16* __restrict__ A,
                                                     const bf16* __restrict__ W,
                                                     const float* __restrict__ resid,
                                                     float* __restrict__ C) {
    __shared__ short As[128 * LDSK];
    __shared__ short Ws[128 * LDSK];
    int tid = threadIdx.x;
    int wave = tid >> 6, lane = tid & 63;
    int wm = (wave >> 1) * 64, wn = (wave & 1) * 64;
    int bm = blockIdx.y * 128, bn = blockIdx.x * 128;
    f32x4 acc[4][4] = {};
    int lr = tid >> 1;
    int lseg = (tid & 1) * 16;
    const int K = DI_;
    int fr = lane & 15, kg = (lane >> 4) * 8;
    for (int k0 = 0; k0 < K; k0 += 32) {
        const short* ag = (const short*)A + (size_t)(bm + lr) * K + k0 + lseg;
        short8 av0 = *(const short8*)ag;
        short8 av1 = *(const short8*)(ag + 8);
        const short* wg = (const short*)W + (size_t)(bn + lr) * K + k0 + lseg;
        short8 wv0 = *(const short8*)wg;
        short8 wv1 = *(const short8*)(wg + 8);
        __syncthreads();
        *(short8*)&As[lr*LDSK + lseg]     = av0;
        *(short8*)&As[lr*LDSK + lseg + 8] = av1;
        *(short8*)&Ws[lr*LDSK + lseg]     = wv0;
        *(short8*)&Ws[lr*LDSK + lseg + 8] = wv1;
        __syncthreads();
        short8 af[4], wf[4];
        #pragma unroll
        for (int i = 0; i < 4; i++)
            af[i] = *(const short8*)&As[(wm + i*16 + fr)*LDSK + kg];
        #pragma unroll
        for (int j = 0; j < 4; j++)
            wf[j] = *(const short8*)&Ws[(wn + j*16 + fr)*LDSK + kg];
        #pragma unroll
        for (int i = 0; i < 4; i++)
            #pragma unroll
            for (int j = 0; j < 4; j++)
                acc[i][j] = __builtin_amdgcn_mfma_f32_16x16x32_bf16(af[i], wf[j], acc[i][j], 0, 0, 0);
    }
    int rg = (lane >> 4) * 4;
    #pragma unroll
    for (int i = 0; i < 4; i++) {
        int mrow = bm + wm + i*16 + rg;
        #pragma unroll
        for (int j = 0; j < 4; j++) {
            int ncol = bn + wn + j*16 + fr;
            #pragma unroll
            for (int r = 0; r < 4; r++) {
                int m = mrow + r;
                C[(size_t)m * DM_ + ncol] = acc[i][j][r] + resid[(size_t)m * DM_ + ncol];
            }
        }
    }
}

// ------------------------------------------------------------------
// Depthwise causal conv7 + SiLU on xbc [8192, 1664] (bf16 -> bf16).
// ------------------------------------------------------------------
__global__ __launch_bounds__(256) void conv_kernel(const bf16* __restrict__ xbc,
                                                   const float* __restrict__ cw,
                                                   const float* __restrict__ cb,
                                                   bf16* __restrict__ out) {
    size_t idx = (size_t)blockIdx.x * 256 + threadIdx.x;
    if (idx >= (size_t)ROWS_ * CD_) return;
    int c = idx % CD_;
    int t = (idx / CD_) % L_;
    int b = idx / ((size_t)CD_ * L_);
    float acc = cb[c];
    #pragma unroll
    for (int j = 0; j < 7; j++) {
        int tt = t - 6 + j;
        if (tt >= 0)
            acc += b2f(xbc[((size_t)(b * L_ + tt)) * CD_ + c]) * cw[c * 7 + j];
    }
    acc = acc / (1.f + __expf(-acc));   // silu
    out[idx] = f2b(acc);
}

// ------------------------------------------------------------------
// dt: softplus(dt2 + bias), with time-flip for backward batches.
// dt4 layout: [(bb*L + t)*NH + h]
// ------------------------------------------------------------------
__global__ __launch_bounds__(256) void dt_kernel(const float* __restrict__ dtr,
                                                 const float* __restrict__ dt_bias,
                                                 float* __restrict__ dt4) {
    int idx = blockIdx.x * 256 + threadIdx.x;
    if (idx >= BB4_ * L_ * NH_) return;
    int h = idx % NH_;
    int t = (idx / NH_) % L_;
    int bbx = idx / (NH_ * L_);
    int bp = bbx & 1;
    float raw;
    if (bbx < 2) raw = dtr[((size_t)(bp * L_ + t)) * 48 + h];
    else         raw = dtr[((size_t)(bp * L_ + (L_ - 1 - t))) * 48 + NH_ + h];
    float v = raw + dt_bias[h];
    float dt = (v > 20.f) ? v : log1pf(__expf(v));
    dt4[idx] = dt;
}

// ------------------------------------------------------------------
// per-chunk inclusive cumsum of dt*A.  Acum layout: [((bb*NH+h)*NC+c)*CH + l]
// ------------------------------------------------------------------
__global__ __launch_bounds__(256) void scan_kernel(const float* __restrict__ dt4,
                                                   const float* __restrict__ A_log,
                                                   float* __restrict__ Acum) {
    int bid = blockIdx.x;          // ((bb*NH+h)*NC+c)
    int c  = bid % NC_;
    int h  = (bid / NC_) % NH_;
    int bbx = bid / (NC_ * NH_);
    int l = threadIdx.x;
    float Ah = -__expf(A_log[h]);
    float val = dt4[((size_t)(bbx * L_) + c * CH_ + l) * NH_ + h] * Ah;
    __shared__ float sc[256];
    sc[l] = val; __syncthreads();
    for (int off = 1; off < 256; off <<= 1) {
        float t = (l >= off) ? sc[l - off] : 0.f;
        __syncthreads();
        sc[l] += t;
        __syncthreads();
    }
    Acum[(size_t)bid * CH_ + l] = sc[l];
}

// ------------------------------------------------------------------
// chunk states: S[n,p] = sum_l B[l,n]*exp(Atot-Acum[l])*X[l,p]
// states layout: [((bb*NC+c)*NH+h)*64*64 + n*64 + p]  (bf16)
// ------------------------------------------------------------------
__global__ __launch_bounds__(256) void states_kernel(const bf16* __restrict__ conv,
                                                     const float* __restrict__ dt4,
                                                     const float* __restrict__ Acum,
                                                     bf16* __restrict__ states) {
    int bid = blockIdx.x;          // (bb*NC+c)*NH + h
    int h = bid % NH_;
    int c = (bid / NH_) % NC_;
    int bbx = bid / (NH_ * NC_);
    int bp = bbx & 1;
    bool flip = bbx >= 2;
    int tid = threadIdx.x;
    int tx = tid & 15, ty = tid >> 4;
    size_t abase = ((size_t)(bbx * NH_ + h) * NC_ + c) * CH_;
    float Atot = Acum[abase + CH_ - 1];
    __shared__ float Bs[64][65];
    __shared__ float Xs[64][65];
    float acc[4][4] = {};
    for (int lt = 0; lt < 4; lt++) {
        for (int rr = 0; rr < 16; rr++) {
            int li = tid + rr * 256;
            int lr = li >> 6, col = li & 63;
            int l = lt * 64 + lr;
            int t = c * CH_ + l;
            int tt = flip ? (L_ - 1 - t) : t;
            size_t ro = ((size_t)(bp * L_ + tt)) * CD_;
            float decay = __expf(Atot - Acum[abase + l]);
            Bs[lr][col] = b2f(conv[ro + DI_ + col]) * decay;
            Xs[lr][col] = b2f(conv[ro + h * HD_ + col]) * dt4[((size_t)(bbx * L_) + t) * NH_ + h];
        }
        __syncthreads();
        for (int l = 0; l < 64; l++) {
            float bv[4], xv[4];
            #pragma unroll
            for (int i = 0; i < 4; i++) bv[i] = Bs[l][i*16 + ty];
            #pragma unroll
            for (int j = 0; j < 4; j++) xv[j] = Xs[l][j*16 + tx];
            #pragma unroll
            for (int i = 0; i < 4; i++)
                #pragma unroll
                for (int j = 0; j < 4; j++)
                    acc[i][j] += bv[i] * xv[j];
        }
        __syncthreads();
    }
    size_t sbase = (size_t)bid * 64 * 64;
    #pragma unroll
    for (int i = 0; i < 4; i++)
        #pragma unroll
        for (int j = 0; j < 4; j++)
            states[sbase + (size_t)(i*16 + ty) * 64 + (j*16 + tx)] = f2b(acc[i][j]);
}

// ------------------------------------------------------------------
// inter-chunk recurrence: prev[c] = prev[c-1]*exp(T_{c-1}) + S_{c-1}
// ------------------------------------------------------------------
__global__ __launch_bounds__(256) void chunkscan_kernel(const bf16* __restrict__ states,
                                                        const float* __restrict__ Acum,
                                                        bf16* __restrict__ prev) {
    int bid = blockIdx.x;  // bb*NH + h
    int h = bid % NH_;
    int bbx = bid / NH_;
    int tid = threadIdx.x;
    float run[16];
    #pragma unroll
    for (int k = 0; k < 16; k++) run[k] = 0.f;
    for (int c = 0; c < NC_; c++) {
        float Tc = Acum[((size_t)(bbx * NH_ + h) * NC_ + c) * CH_ + CH_ - 1];
        float ec = __expf(Tc);
        size_t base = ((size_t)(bbx * NC_ + c) * NH_ + h) * 4096;
        #pragma unroll
        for (int k = 0; k < 16; k++) {
            size_t e = tid + k * 256;
            prev[base + e] = f2b(run[k]);
            run[k] = run[k] * ec + b2f(states[base + e]);
        }
    }
}

// ------------------------------------------------------------------
// Y = Y_diag + Y_off per (b,c,h,l-tile of 64).
// pass 0: forward batches (bbx = b), write yc[b, t+1] = y   (t==L-1 -> zero row 0)
// pass 1: backward batches (bbx = b+2), yc[b, L-2-t] += y   (t==L-1 dropped)
// ------------------------------------------------------------------
__global__ __launch_bounds__(256) void ydiag_kernel(const bf16* __restrict__ conv,
                                                    const float* __restrict__ dt4,
                                                    const float* __restrict__ Acum,
                                                    const bf16* __restrict__ prev,
                                                    bf16* __restrict__ yc,
                                                    int pass) {
    int bid = blockIdx.x;   // ((b*NC+c)*NH+h)*4 + lt   (b in 0..1)
    int lt = bid & 3;
    int q  = bid >> 2;
    int h  = q % NH_;
    int r  = q / NH_;
    int c  = r % NC_;
    int b  = r / NC_;
    int bbx = pass ? (b + 2) : b;
    int bp = b;
    bool flip = pass != 0;
    int tid = threadIdx.x;
    int tx = tid & 15, ty = tid >> 4;
    size_t abase = ((size_t)(bbx * NH_ + h) * NC_ + c) * CH_;

    __shared__ float Cs[64][65];
    __shared__ float Bs[64][65];   // prev / B tile, then reused for G
    __shared__ float Xs[64][65];
    __shared__ float aL[64], aS[64];

    for (int rr = 0; rr < 16; rr++) {
        int li = tid + rr * 256;
        int lr = li >> 6, col = li & 63;
        int l = lt * 64 + lr;
        int t = c * CH_ + l;
        int tt = flip ? (L_ - 1 - t) : t;
        Cs[lr][col] = b2f(conv[((size_t)(bp * L_ + tt)) * CD_ + DI_ + DS_ + col]);
    }
    {
        size_t pbase = ((size_t)(bbx * NC_ + c) * NH_ + h) * 4096;
        for (int rr = 0; rr < 16; rr++) {
            int li = tid + rr * 256;
            Bs[li >> 6][li & 63] = b2f(prev[pbase + li]);
        }
    }
    if (tid < 64) aL[tid] = Acum[abase + lt * 64 + tid];
    __syncthreads();

    float acc[4][4] = {};
    for (int n = 0; n < 64; n++) {
        float cv[4], pv[4];
        #pragma unroll
        for (int i = 0; i < 4; i++) cv[i] = Cs[i*16 + ty][n];
        #pragma unroll
        for (int j = 0; j < 4; j++) pv[j] = Bs[n][j*16 + tx];
        #pragma unroll
        for (int i = 0; i < 4; i++)
            #pragma unroll
            for (int j = 0; j < 4; j++)
                acc[i][j] += cv[i] * pv[j];
    }
    #pragma unroll
    for (int i = 0; i < 4; i++) {
        float e = __expf(aL[i*16 + ty]);
        #pragma unroll
        for (int j = 0; j < 4; j++) acc[i][j] *= e;
    }
    __syncthreads();

    for (int st = 0; st <= lt; st++) {
        for (int rr = 0; rr < 16; rr++) {
            int li = tid + rr * 256;
            int sr = li >> 6, col = li & 63;
            int s = st * 64 + sr;
            int t = c * CH_ + s;
            int tt = flip ? (L_ - 1 - t) : t;
            size_t ro = ((size_t)(bp * L_ + tt)) * CD_;
            Bs[sr][col] = b2f(conv[ro + DI_ + col]);
            Xs[sr][col] = b2f(conv[ro + h * HD_ + col]) * dt4[((size_t)(bbx * L_) + t) * NH_ + h];
        }
        if (tid < 64) aS[tid] = Acum[abase + st * 64 + tid];
        __syncthreads();
        float gacc[4][4] = {};
        for (int n = 0; n < 64; n++) {
            float cv[4], bv[4];
            #pragma unroll
            for (int i = 0; i < 4; i++) cv[i] = Cs[i*16 + ty][n];
            #pragma unroll
            for (int j = 0; j < 4; j++) bv[j] = Bs[j*16 + tx][n];
            #pragma unroll
            for (int i = 0; i < 4; i++)
                #pragma unroll
                for (int j = 0; j < 4; j++)
                    gacc[i][j] += cv[i] * bv[j];
        }
        __syncthreads();
        #pragma unroll
        for (int i = 0; i < 4; i++) {
            int l = i*16 + ty;
            #pragma unroll
            for (int j = 0; j < 4; j++) {
                int s = j*16 + tx;
                bool valid = (st < lt) || (l >= s);
                Bs[l][s] = valid ? gacc[i][j] * __expf(aL[l] - aS[s]) : 0.f;
            }
        }
        __syncthreads();
        for (int s = 0; s < 64; s++) {
            float gv[4], xv[4];
            #pragma unroll
            for (int i = 0; i < 4; i++) gv[i] = Bs[i*16 + ty][s];
            #pragma unroll
            for (int j = 0; j < 4; j++) xv[j] = Xs[s][j*16 + tx];
            #pragma unroll
            for (int i = 0; i < 4; i++)
                #pragma unroll
                for (int j = 0; j < 4; j++)
                    acc[i][j] += gv[i] * xv[j];
        }
        __syncthreads();
    }

    #pragma unroll
    for (int i = 0; i < 4; i++) {
        int l = i*16 + ty;
        int t = c * CH_ + lt * 64 + l;
        #pragma unroll
        for (int j = 0; j < 4; j++) {
            int p = j*16 + tx;
            float v = acc[i][j];
            if (!pass) {
                int pos = t + 1;
                if (pos == L_)
                    yc[((size_t)(b * L_) + 0) * DI_ + h * HD_ + p] = f2b(0.f);
                else
                    yc[((size_t)(b * L_) + pos) * DI_ + h * HD_ + p] = f2b(v);
            } else {
                int pos = L_ - 2 - t;
                if (pos >= 0) {
                    size_t o = ((size_t)(b * L_) + pos) * DI_ + h * HD_ + p;
                    yc[o] = f2b(b2f(yc[o]) + v);
                }
            }
        }
    }
}

// ------------------------------------------------------------------
// combine: D-term GEMV, silu(z) gate, RMSNorm
// ------------------------------------------------------------------
__global__ __launch_bounds__(256) void combine_kernel(const bf16* __restrict__ yc,
                                                      const bf16* __restrict__ conv,
                                                      const bf16* __restrict__ zbuf,
                                                      const float* __restrict__ fcD,
                                                      const float* __restrict__ Dvec,
                                                      const float* __restrict__ rms_w,
                                                      bf16* __restrict__ ybuf) {
    int row = blockIdx.x;   // b*L + t
    int tid = threadIdx.x;
    __shared__ float xog_s[DI_];
    __shared__ float dterm_s[NH_];
    __shared__ float rs[4];
    __shared__ float scale_s;
    float yv[6], xog[6], zv[6];
    const bf16* convrow = conv + (size_t)row * CD_;
    const bf16* zrow = zbuf + (size_t)row * DI_;
    const bf16* ycrow = yc + (size_t)row * DI_;
    #pragma unroll
    for (int k = 0; k < 6; k++) {
        int d = tid + k * 256;
        float xo = b2f(convrow[d]);
        xog[k] = xo; xog_s[d] = xo;
        zv[k] = b2f(zrow[d]);
        yv[k] = b2f(ycrow[d]);
    }
    __syncthreads();
    int wid = tid >> 6, lane = tid & 63;
    for (int hh = 0; hh < 6; hh++) {
        int h = wid * 6 + hh;
        float s = 0.f;
        #pragma unroll
        for (int k = 0; k < 24; k++) {
            int d = lane + k * 64;
            s += xog_s[d] * fcD[(size_t)h * DI_ + d];
        }
        for (int off = 32; off > 0; off >>= 1) s += __shfl_down(s, off);
        if (!lane) dterm_s[h] = s + Dvec[h];
    }
    __syncthreads();
    float ss = 0.f;
    #pragma unroll
    for (int k = 0; k < 6; k++) {
        int d = tid + k * 256;
        int h = d >> 6;
        float y = yv[k] + xog[k] * dterm_s[h];
        float z = zv[k];
        y *= z / (1.f + __expf(-z));
        yv[k] = y;
        ss += y * y;
    }
    for (int off = 32; off > 0; off >>= 1) ss += __shfl_down(ss, off);
    if (!lane) rs[wid] = ss;
    __syncthreads();
    if (!tid) scale_s = rsqrtf((rs[0]+rs[1]+rs[2]+rs[3]) / (float)DI_ + EPS_);
    __syncthreads();
    float sc = scale_s;
    bf16* yrow = ybuf + (size_t)row * DI_;
    #pragma unroll
    for (int k = 0; k < 6; k++) {
        int d = tid + k * 256;
        yrow[d] = f2b(yv[k] * sc * rms_w[d]);
    }
}

// ------------------------------------------------------------------
extern "C" void kernel_launch(void* const* d_in, const int* in_sizes, int n_in,
                              void* d_out, int out_size, void* d_ws, size_t ws_size,
                              hipStream_t stream) {
    const float* x        = (const float*)d_in[0];
    const float* ln_w     = (const float*)d_in[1];
    const float* ln_b     = (const float*)d_in[2];
    const float* in_proj  = (const float*)d_in[3];
    const float* conv_w   = (const float*)d_in[4];
    const float* conv_b   = (const float*)d_in[5];
    const float* dt_bias  = (const float*)d_in[6];
    const float* A_log    = (const float*)d_in[7];
    const float* Dvec     = (const float*)d_in[8];
    const float* fc_D_w   = (const float*)d_in[9];
    const float* rms_w    = (const float*)d_in[10];
    const float* out_proj = (const float*)d_in[11];
    float* out = (float*)d_out;

    // ---- workspace layout (lifetime-aliased), ~117 MB total ----
    uint8_t* base = (uint8_t*)d_ws;
    size_t off = 0;
    auto alloc = [&](size_t bytes) -> void* {
        void* p = base + off;
        off += (bytes + 255) & ~(size_t)255;
        return p;
    };
    bf16*  buf_z    = (bf16*) alloc((size_t)ROWS_ * DI_ * 2);            // 25.2 MB [2..9]
    uint8_t* regA   = (uint8_t*)alloc((size_t)ROWS_ * CD_ * 2);          // 27.3 MB xbc[2..3]/st+prev[6..8]/y[9..10]
    float* buf_dtr  = (float*)alloc((size_t)ROWS_ * 48 * 4);             // 1.6 MB  [2..4]
    bf16*  buf_conv = (bf16*) alloc((size_t)ROWS_ * CD_ * 2);            // 27.3 MB [3..9]
    float* buf_dt   = (float*)alloc((size_t)BB4_ * L_ * NH_ * 4);        // 1.6 MB
    float* buf_acum = (float*)alloc((size_t)BB4_ * NH_ * NC_ * CH_ * 4); // 1.6 MB
    uint8_t* regB   = (uint8_t*)alloc((size_t)ROWS_ * DM_ * 4);          // 25.2 MB u[1..2]/yc[8..9]
    bf16*  w_in_bf  = (bf16*) alloc((size_t)DIP_ * DM_ * 2);             // 5.0 MB
    bf16*  w_out_bf = (bf16*) alloc((size_t)DM_ * DI_ * 2);              // 2.4 MB

    bf16*  buf_xbc  = (bf16*)regA;
    bf16*  buf_st   = (bf16*)regA;                                   // 12.6 MB
    bf16*  buf_prev = buf_st + (size_t)BB4_ * NC_ * NH_ * 4096;      // 12.6 MB
    bf16*  buf_y    = (bf16*)regA;
    bf16*  buf_u    = (bf16*)regB;
    bf16*  buf_yc   = (bf16*)regB;

    // 0. weight casts (graph-safe, every call)
    cast_f2b<<<(DIP_ * DM_ / 4 + 255) / 256, 256, 0, stream>>>(in_proj, w_in_bf, DIP_ * DM_);
    cast_f2b<<<(DM_ * DI_ / 4 + 255) / 256, 256, 0, stream>>>(out_proj, w_out_bf, DM_ * DI_);
    // 1. LayerNorm (bf16 out)
    ln_kernel<<<ROWS_, 256, 0, stream>>>(x, ln_w, ln_b, buf_u);
    // 2. in_proj GEMM (bf16 MFMA) with split outputs
    gemm_bf16_inproj<<<dim3((DIP_ + 127) / 128, ROWS_ / 128), 256, 0, stream>>>(
        buf_u, w_in_bf, buf_z, buf_xbc, buf_dtr);
    // 3. conv + silu
    {
        size_t tot = (size_t)ROWS_ * CD_;
        conv_kernel<<<(tot + 255) / 256, 256, 0, stream>>>(buf_xbc, conv_w, conv_b, buf_conv);
    }
    // 4. dt
    dt_kernel<<<(BB4_ * L_ * NH_) / 256, 256, 0, stream>>>(buf_dtr, dt_bias, buf_dt);
    // 5. per-chunk cumsum of dt*A
    scan_kernel<<<BB4_ * NH_ * NC_, 256, 0, stream>>>(buf_dt, A_log, buf_acum);
    // 6. chunk states
    states_kernel<<<BB4_ * NC_ * NH_, 256, 0, stream>>>(buf_conv, buf_dt, buf_acum, buf_st);
    // 7. inter-chunk scan
    chunkscan_kernel<<<BB4_ * NH_, 256, 0, stream>>>(buf_st, buf_acum, buf_prev);
    // 8. Y = diag + off, fused roll/flip/add (two ordered passes)
    ydiag_kernel<<<B_ * NC_ * NH_ * 4, 256, 0, stream>>>(buf_conv, buf_dt, buf_acum, buf_prev, buf_yc, 0);
    ydiag_kernel<<<B_ * NC_ * NH_ * 4, 256, 0, stream>>>(buf_conv, buf_dt, buf_acum, buf_prev, buf_yc, 1);
    // 9. combine + D-term + gate + RMSNorm
    combine_kernel<<<ROWS_, 256, 0, stream>>>(buf_yc, buf_conv, buf_z, fc_D_w, Dvec, rms_w, buf_y);
    // 10. out_proj GEMM (bf16 MFMA) + residual
    gemm_bf16_out<<<dim3(DM_ / 128, ROWS_ / 128), 256, 0, stream>>>(
        buf_y, w_out_bf, x, out);
}

// Round 5
// 547.570 us; speedup vs baseline: 3.4242x; 1.7847x over previous
//
#include <hip/hip_runtime.h>
#include <hip/hip_bf16.h>
#include <cstdint>
#include <cstddef>

typedef __hip_bfloat16 bf16;
typedef __attribute__((ext_vector_type(8))) short short8;
typedef __attribute__((ext_vector_type(4))) float f32x4;

// ---- problem constants ----
#define B_   2
#define L_   4096
#define DM_  768      // d_model
#define DI_  1536     // d_inner
#define NH_  24       // nheads
#define HD_  64       // headdim
#define DS_  64       // d_state
#define CH_  256      // chunk
#define NC_  16       // n chunks
#define CD_  1664     // conv dim
#define DIP_ 3248     // d_in_proj
#define EPS_ 1e-5f

#define ROWS_ (B_*L_)        // 8192
#define BB4_  (2*B_)         // 4 ssd batches

#define LDSK 40              // GEMM LDS row stride (shorts)
#define LDT  72              // SSD MFMA tile row stride (shorts; 144B = 9x16B)

__device__ __forceinline__ float b2f(bf16 v) { return __bfloat162float(v); }
__device__ __forceinline__ bf16  f2b(float v) { return __float2bfloat16(v); }
__device__ __forceinline__ float sb2f(short s) {
    bf16 t; __builtin_memcpy(&t, &s, 2); return __bfloat162float(t);
}
__device__ __forceinline__ short f2s(float v) {
    bf16 t = __float2bfloat16(v); short s; __builtin_memcpy(&s, &t, 2); return s;
}

// ------------------------------------------------------------------
// cast f32 -> bf16 (weights)
// ------------------------------------------------------------------
__global__ __launch_bounds__(256) void cast_f2b(const float* __restrict__ s,
                                                bf16* __restrict__ d, int n) {
    int i = (blockIdx.x * 256 + threadIdx.x) * 4;
    if (i + 3 < n) {
        float4 v = *(const float4*)(s + i);
        d[i]   = f2b(v.x); d[i+1] = f2b(v.y);
        d[i+2] = f2b(v.z); d[i+3] = f2b(v.w);
    } else {
        for (int k = i; k < n; k++) d[k] = f2b(s[k]);
    }
}

// ------------------------------------------------------------------
// LayerNorm: one block per row (768), bf16 out
// ------------------------------------------------------------------
__global__ __launch_bounds__(256) void ln_kernel(const float* __restrict__ x,
                                                 const float* __restrict__ w,
                                                 const float* __restrict__ bb,
                                                 bf16* __restrict__ u) {
    int row = blockIdx.x, tid = threadIdx.x;
    const float* xr = x + (size_t)row * DM_;
    float v0 = xr[tid], v1 = xr[tid + 256], v2 = xr[tid + 512];
    float s = v0 + v1 + v2;
    float q = v0*v0 + v1*v1 + v2*v2;
    for (int off = 32; off > 0; off >>= 1) {
        s += __shfl_down(s, off);
        q += __shfl_down(q, off);
    }
    __shared__ float rs[4], rq[4];
    __shared__ float mean_s, rstd_s;
    int lane = tid & 63, wid = tid >> 6;
    if (!lane) { rs[wid] = s; rq[wid] = q; }
    __syncthreads();
    if (!tid) {
        float S = rs[0]+rs[1]+rs[2]+rs[3];
        float Q = rq[0]+rq[1]+rq[2]+rq[3];
        float mu = S / (float)DM_;
        float var = Q / (float)DM_ - mu*mu;
        mean_s = mu; rstd_s = rsqrtf(var + EPS_);
    }
    __syncthreads();
    float mu = mean_s, rstd = rstd_s;
    bf16* ur = u + (size_t)row * DM_;
    ur[tid]       = f2b((v0 - mu) * rstd * w[tid]       + bb[tid]);
    ur[tid + 256] = f2b((v1 - mu) * rstd * w[tid + 256] + bb[tid + 256]);
    ur[tid + 512] = f2b((v2 - mu) * rstd * w[tid + 512] + bb[tid + 512]);
}

// ------------------------------------------------------------------
// MFMA bf16 GEMM (in_proj): C[8192,3248] = u @ W^T, split epilogue
// ------------------------------------------------------------------
__global__ __launch_bounds__(256) void gemm_bf16_inproj(const bf16* __restrict__ A,
                                                        const bf16* __restrict__ W,
                                                        bf16* __restrict__ zbuf,
                                                        bf16* __restrict__ xbc,
                                                        float* __restrict__ dtr) {
    __shared__ short As[128 * LDSK];
    __shared__ short Ws[128 * LDSK];
    int tid = threadIdx.x;
    int wave = tid >> 6, lane = tid & 63;
    int wm = (wave >> 1) * 64, wn = (wave & 1) * 64;
    int bm = blockIdx.y * 128, bn = blockIdx.x * 128;
    f32x4 acc[4][4] = {};
    int lr = tid >> 1;
    int lseg = (tid & 1) * 16;
    const int K = DM_;
    int fr = lane & 15, kg = (lane >> 4) * 8;
    for (int k0 = 0; k0 < K; k0 += 32) {
        const short* ag = (const short*)A + (size_t)(bm + lr) * K + k0 + lseg;
        short8 av0 = *(const short8*)ag;
        short8 av1 = *(const short8*)(ag + 8);
        short8 wv0 = {}, wv1 = {};
        int n = bn + lr;
        if (n < DIP_) {
            const short* wg = (const short*)W + (size_t)n * K + k0 + lseg;
            wv0 = *(const short8*)wg;
            wv1 = *(const short8*)(wg + 8);
        }
        __syncthreads();
        *(short8*)&As[lr*LDSK + lseg]     = av0;
        *(short8*)&As[lr*LDSK + lseg + 8] = av1;
        *(short8*)&Ws[lr*LDSK + lseg]     = wv0;
        *(short8*)&Ws[lr*LDSK + lseg + 8] = wv1;
        __syncthreads();
        short8 af[4], wf[4];
        #pragma unroll
        for (int i = 0; i < 4; i++)
            af[i] = *(const short8*)&As[(wm + i*16 + fr)*LDSK + kg];
        #pragma unroll
        for (int j = 0; j < 4; j++)
            wf[j] = *(const short8*)&Ws[(wn + j*16 + fr)*LDSK + kg];
        #pragma unroll
        for (int i = 0; i < 4; i++)
            #pragma unroll
            for (int j = 0; j < 4; j++)
                acc[i][j] = __builtin_amdgcn_mfma_f32_16x16x32_bf16(af[i], wf[j], acc[i][j], 0, 0, 0);
    }
    int rg = (lane >> 4) * 4;
    #pragma unroll
    for (int i = 0; i < 4; i++) {
        int mrow = bm + wm + i*16 + rg;
        #pragma unroll
        for (int j = 0; j < 4; j++) {
            int ncol = bn + wn + j*16 + fr;
            #pragma unroll
            for (int r = 0; r < 4; r++) {
                float v = acc[i][j][r];
                int m = mrow + r;
                if (ncol < DI_)            zbuf[(size_t)m * DI_ + ncol] = f2b(v);
                else if (ncol < DI_ + CD_) xbc[(size_t)m * CD_ + (ncol - DI_)] = f2b(v);
                else if (ncol < DIP_)      dtr[(size_t)m * 48 + (ncol - DI_ - CD_)] = v;
            }
        }
    }
}

// ------------------------------------------------------------------
// MFMA bf16 GEMM (out_proj): out = y @ W^T + x
// ------------------------------------------------------------------
__global__ __launch_bounds__(256) void gemm_bf16_out(const bf16* __restrict__ A,
                                                     const bf16* __restrict__ W,
                                                     const float* __restrict__ resid,
                                                     float* __restrict__ C) {
    __shared__ short As[128 * LDSK];
    __shared__ short Ws[128 * LDSK];
    int tid = threadIdx.x;
    int wave = tid >> 6, lane = tid & 63;
    int wm = (wave >> 1) * 64, wn = (wave & 1) * 64;
    int bm = blockIdx.y * 128, bn = blockIdx.x * 128;
    f32x4 acc[4][4] = {};
    int lr = tid >> 1;
    int lseg = (tid & 1) * 16;
    const int K = DI_;
    int fr = lane & 15, kg = (lane >> 4) * 8;
    for (int k0 = 0; k0 < K; k0 += 32) {
        const short* ag = (const short*)A + (size_t)(bm + lr) * K + k0 + lseg;
        short8 av0 = *(const short8*)ag;
        short8 av1 = *(const short8*)(ag + 8);
        const short* wg = (const short*)W + (size_t)(bn + lr) * K + k0 + lseg;
        short8 wv0 = *(const short8*)wg;
        short8 wv1 = *(const short8*)(wg + 8);
        __syncthreads();
        *(short8*)&As[lr*LDSK + lseg]     = av0;
        *(short8*)&As[lr*LDSK + lseg + 8] = av1;
        *(short8*)&Ws[lr*LDSK + lseg]     = wv0;
        *(short8*)&Ws[lr*LDSK + lseg + 8] = wv1;
        __syncthreads();
        short8 af[4], wf[4];
        #pragma unroll
        for (int i = 0; i < 4; i++)
            af[i] = *(const short8*)&As[(wm + i*16 + fr)*LDSK + kg];
        #pragma unroll
        for (int j = 0; j < 4; j++)
            wf[j] = *(const short8*)&Ws[(wn + j*16 + fr)*LDSK + kg];
        #pragma unroll
        for (int i = 0; i < 4; i++)
            #pragma unroll
            for (int j = 0; j < 4; j++)
                acc[i][j] = __builtin_amdgcn_mfma_f32_16x16x32_bf16(af[i], wf[j], acc[i][j], 0, 0, 0);
    }
    int rg = (lane >> 4) * 4;
    #pragma unroll
    for (int i = 0; i < 4; i++) {
        int mrow = bm + wm + i*16 + rg;
        #pragma unroll
        for (int j = 0; j < 4; j++) {
            int ncol = bn + wn + j*16 + fr;
            #pragma unroll
            for (int r = 0; r < 4; r++) {
                int m = mrow + r;
                C[(size_t)m * DM_ + ncol] = acc[i][j][r] + resid[(size_t)m * DM_ + ncol];
            }
        }
    }
}

// ------------------------------------------------------------------
// Depthwise causal conv7 + SiLU (bf16 -> bf16)
// ------------------------------------------------------------------
__global__ __launch_bounds__(256) void conv_kernel(const bf16* __restrict__ xbc,
                                                   const float* __restrict__ cw,
                                                   const float* __restrict__ cb,
                                                   bf16* __restrict__ out) {
    size_t idx = (size_t)blockIdx.x * 256 + threadIdx.x;
    if (idx >= (size_t)ROWS_ * CD_) return;
    int c = idx % CD_;
    int t = (idx / CD_) % L_;
    int b = idx / ((size_t)CD_ * L_);
    float acc = cb[c];
    #pragma unroll
    for (int j = 0; j < 7; j++) {
        int tt = t - 6 + j;
        if (tt >= 0)
            acc += b2f(xbc[((size_t)(b * L_ + tt)) * CD_ + c]) * cw[c * 7 + j];
    }
    acc = acc / (1.f + __expf(-acc));   // silu
    out[idx] = f2b(acc);
}

// ------------------------------------------------------------------
// dt: softplus(dt2 + bias) with flip for bwd batches
// ------------------------------------------------------------------
__global__ __launch_bounds__(256) void dt_kernel(const float* __restrict__ dtr,
                                                 const float* __restrict__ dt_bias,
                                                 float* __restrict__ dt4) {
    int idx = blockIdx.x * 256 + threadIdx.x;
    if (idx >= BB4_ * L_ * NH_) return;
    int h = idx % NH_;
    int t = (idx / NH_) % L_;
    int bbx = idx / (NH_ * L_);
    int bp = bbx & 1;
    float raw;
    if (bbx < 2) raw = dtr[((size_t)(bp * L_ + t)) * 48 + h];
    else         raw = dtr[((size_t)(bp * L_ + (L_ - 1 - t))) * 48 + NH_ + h];
    float v = raw + dt_bias[h];
    float dt = (v > 20.f) ? v : log1pf(__expf(v));
    dt4[idx] = dt;
}

// ------------------------------------------------------------------
// per-chunk inclusive cumsum of dt*A
// ------------------------------------------------------------------
__global__ __launch_bounds__(256) void scan_kernel(const float* __restrict__ dt4,
                                                   const float* __restrict__ A_log,
                                                   float* __restrict__ Acum) {
    int bid = blockIdx.x;          // ((bb*NH+h)*NC+c)
    int c  = bid % NC_;
    int h  = (bid / NC_) % NH_;
    int bbx = bid / (NC_ * NH_);
    int l = threadIdx.x;
    float Ah = -__expf(A_log[h]);
    float val = dt4[((size_t)(bbx * L_) + c * CH_ + l) * NH_ + h] * Ah;
    __shared__ float sc[256];
    sc[l] = val; __syncthreads();
    for (int off = 1; off < 256; off <<= 1) {
        float t = (l >= off) ? sc[l - off] : 0.f;
        __syncthreads();
        sc[l] += t;
        __syncthreads();
    }
    Acum[(size_t)bid * CH_ + l] = sc[l];
}

// ------------------------------------------------------------------
// chunk states (MFMA): S_T[p][n] = sum_l X~[l,p] * Bd[l,n]
// states layout TRANSPOSED: [((bb*NC+c)*NH+h)*4096 + p*64 + n]
// ------------------------------------------------------------------
__global__ __launch_bounds__(256) void states_kernel(const bf16* __restrict__ conv,
                                                     const float* __restrict__ dt4,
                                                     const float* __restrict__ Acum,
                                                     bf16* __restrict__ states) {
    int bid = blockIdx.x;          // (bbx*NC+c)*NH + h
    int h = bid % NH_;
    int c = (bid / NH_) % NC_;
    int bbx = bid / (NH_ * NC_);
    int bp = bbx & 1;
    bool flip = bbx >= 2;
    int tid = threadIdx.x;
    int wave = tid >> 6, lane = tid & 63;
    int wr = wave >> 1, wc = wave & 1;
    int fr = lane & 15, kg = (lane >> 4) * 8, rg = (lane >> 4) * 4;
    size_t abase = ((size_t)(bbx * NH_ + h) * NC_ + c) * CH_;
    float Atot = Acum[abase + CH_ - 1];

    __shared__ short Xt[64 * LDT];   // [p][l]
    __shared__ short Bdt[64 * LDT];  // [n][l]
    f32x4 acc[2][2] = {};

    for (int lt = 0; lt < 4; lt++) {
        __syncthreads();
        int l = tid & 63;
        int q0 = (tid >> 6) * 8;
        int t = c * CH_ + lt * 64 + l;
        int tt = flip ? (L_ - 1 - t) : t;
        const short* crow = (const short*)conv + (size_t)(bp * L_ + tt) * CD_;
        float dtv = dt4[((size_t)(bbx * L_) + t) * NH_ + h];
        float decay = __expf(Atot - Acum[abase + lt * 64 + l]);
        #pragma unroll
        for (int half = 0; half < 2; half++) {
            int qq = q0 + half * 32;
            short8 xv = *(const short8*)(crow + h * HD_ + qq);
            short8 bv = *(const short8*)(crow + DI_ + qq);
            #pragma unroll
            for (int k = 0; k < 8; k++) {
                Xt[(qq + k) * LDT + l]  = f2s(sb2f(xv[k]) * dtv);
                Bdt[(qq + k) * LDT + l] = f2s(sb2f(bv[k]) * decay);
            }
        }
        __syncthreads();
        #pragma unroll
        for (int ks = 0; ks < 2; ks++) {
            short8 af[2], wf[2];
            #pragma unroll
            for (int i = 0; i < 2; i++)
                af[i] = *(const short8*)&Xt[(wr*32 + i*16 + fr)*LDT + ks*32 + kg];
            #pragma unroll
            for (int j = 0; j < 2; j++)
                wf[j] = *(const short8*)&Bdt[(wc*32 + j*16 + fr)*LDT + ks*32 + kg];
            #pragma unroll
            for (int i = 0; i < 2; i++)
                #pragma unroll
                for (int j = 0; j < 2; j++)
                    acc[i][j] = __builtin_amdgcn_mfma_f32_16x16x32_bf16(af[i], wf[j], acc[i][j], 0, 0, 0);
        }
    }
    size_t sbase = (size_t)bid * 4096;
    #pragma unroll
    for (int i = 0; i < 2; i++)
        #pragma unroll
        for (int j = 0; j < 2; j++)
            #pragma unroll
            for (int r = 0; r < 4; r++) {
                int p = wr*32 + i*16 + rg + r;
                int n = wc*32 + j*16 + fr;
                states[sbase + p*64 + n] = f2b(acc[i][j][r]);
            }
}

// ------------------------------------------------------------------
// inter-chunk recurrence (elementwise over the 64x64 tile, layout-agnostic)
// ------------------------------------------------------------------
__global__ __launch_bounds__(256) void chunkscan_kernel(const bf16* __restrict__ states,
                                                        const float* __restrict__ Acum,
                                                        bf16* __restrict__ prev) {
    int bid = blockIdx.x;  // bb*NH + h
    int h = bid % NH_;
    int bbx = bid / NH_;
    int tid = threadIdx.x;
    float run[16];
    #pragma unroll
    for (int k = 0; k < 16; k++) run[k] = 0.f;
    for (int c = 0; c < NC_; c++) {
        float Tc = Acum[((size_t)(bbx * NH_ + h) * NC_ + c) * CH_ + CH_ - 1];
        float ec = __expf(Tc);
        size_t base = ((size_t)(bbx * NC_ + c) * NH_ + h) * 4096;
        #pragma unroll
        for (int k = 0; k < 16; k++) {
            size_t e = tid + k * 256;
            prev[base + e] = f2b(run[k]);
            run[k] = run[k] * ec + b2f(states[base + e]);
        }
    }
}

// ------------------------------------------------------------------
// Y = Y_diag + Y_off (MFMA) per (b,c,h,lt). prev stored [p][n].
// pass 0: yc[b, t+1] = y (t==L-1 -> zero row 0)
// pass 1: yc[b, L-2-t] += y (t==L-1 dropped)
// ------------------------------------------------------------------
__global__ __launch_bounds__(256) void ydiag_kernel(const bf16* __restrict__ conv,
                                                    const float* __restrict__ dt4,
                                                    const float* __restrict__ Acum,
                                                    const bf16* __restrict__ prev,
                                                    bf16* __restrict__ yc,
                                                    int pass) {
    int bid = blockIdx.x;   // ((b*NC+c)*NH+h)*4 + lt
    int lt = bid & 3;
    int q  = bid >> 2;
    int h  = q % NH_;
    int r2 = q / NH_;
    int c  = r2 % NC_;
    int b  = r2 / NC_;
    int bbx = pass ? (b + 2) : b;
    int bp = b;
    bool flip = pass != 0;
    int tid = threadIdx.x;
    int wave = tid >> 6, lane = tid & 63;
    int wr = wave >> 1, wc = wave & 1;
    int fr = lane & 15, kg = (lane >> 4) * 8, rg = (lane >> 4) * 4;
    size_t abase = ((size_t)(bbx * NH_ + h) * NC_ + c) * CH_;

    __shared__ short Ct[64 * LDT];   // C tile [l][n]
    __shared__ short Pt[64 * LDT];   // prev [p][n], then B tile [s][n]
    __shared__ short Xt[64 * LDT];   // X^T [p][s]
    __shared__ short Gt[64 * LDT];   // G~ [l][s]
    __shared__ float aL[64], aS[64];

    // stage Ct + Pt + aL
    #pragma unroll
    for (int it = 0; it < 2; it++) {
        int li = tid + it * 256;
        int l = li >> 3, cs = (li & 7) * 8;
        int t = c * CH_ + lt * 64 + l;
        int tt = flip ? (L_ - 1 - t) : t;
        *(short8*)&Ct[l * LDT + cs] =
            *(const short8*)((const short*)conv + (size_t)(bp * L_ + tt) * CD_ + DI_ + DS_ + cs);
    }
    {
        size_t pbase = ((size_t)(bbx * NC_ + c) * NH_ + h) * 4096;
        #pragma unroll
        for (int it = 0; it < 2; it++) {
            int li = tid + it * 256;
            int p = li >> 3, cs = (li & 7) * 8;
            *(short8*)&Pt[p * LDT + cs] =
                *(const short8*)((const short*)prev + pbase + p * 64 + cs);
        }
    }
    if (tid < 64) aL[tid] = Acum[abase + lt * 64 + tid];
    __syncthreads();

    // Y_off = (C @ prevT^T) * exp(aL[l])
    f32x4 acc[2][2] = {};
    #pragma unroll
    for (int ks = 0; ks < 2; ks++) {
        short8 af[2], wf[2];
        #pragma unroll
        for (int i = 0; i < 2; i++)
            af[i] = *(const short8*)&Ct[(wr*32 + i*16 + fr)*LDT + ks*32 + kg];
        #pragma unroll
        for (int j = 0; j < 2; j++)
            wf[j] = *(const short8*)&Pt[(wc*32 + j*16 + fr)*LDT + ks*32 + kg];
        #pragma unroll
        for (int i = 0; i < 2; i++)
            #pragma unroll
            for (int j = 0; j < 2; j++)
                acc[i][j] = __builtin_amdgcn_mfma_f32_16x16x32_bf16(af[i], wf[j], acc[i][j], 0, 0, 0);
    }
    #pragma unroll
    for (int i = 0; i < 2; i++)
        #pragma unroll
        for (int r = 0; r < 4; r++) {
            float e = __expf(aL[wr*32 + i*16 + rg + r]);
            #pragma unroll
            for (int j = 0; j < 2; j++) acc[i][j][r] *= e;
        }

    // diagonal blocks
    for (int st = 0; st <= lt; st++) {
        __syncthreads();   // prior reads of Pt/Xt/Gt complete
        // Bt (natural [s][n]) into Pt
        #pragma unroll
        for (int it = 0; it < 2; it++) {
            int li = tid + it * 256;
            int s = li >> 3, cs = (li & 7) * 8;
            int t = c * CH_ + st * 64 + s;
            int tt = flip ? (L_ - 1 - t) : t;
            *(short8*)&Pt[s * LDT + cs] =
                *(const short8*)((const short*)conv + (size_t)(bp * L_ + tt) * CD_ + DI_ + cs);
        }
        // Xt[p][s] = conv[t(s)][h*64+p] * dt(t)
        {
            int s = tid & 63;
            int p0 = (tid >> 6) * 8;
            int t = c * CH_ + st * 64 + s;
            int tt = flip ? (L_ - 1 - t) : t;
            const short* crow = (const short*)conv + (size_t)(bp * L_ + tt) * CD_ + h * HD_;
            float dtv = dt4[((size_t)(bbx * L_) + t) * NH_ + h];
            #pragma unroll
            for (int half = 0; half < 2; half++) {
                int p = p0 + half * 32;
                short8 xv = *(const short8*)(crow + p);
                #pragma unroll
                for (int k = 0; k < 8; k++)
                    Xt[(p + k) * LDT + s] = f2s(sb2f(xv[k]) * dtv);
            }
        }
        if (tid < 64) aS[tid] = Acum[abase + st * 64 + tid];
        __syncthreads();
        // G = C @ B^T
        f32x4 gacc[2][2] = {};
        #pragma unroll
        for (int ks = 0; ks < 2; ks++) {
            short8 af[2], wf[2];
            #pragma unroll
            for (int i = 0; i < 2; i++)
                af[i] = *(const short8*)&Ct[(wr*32 + i*16 + fr)*LDT + ks*32 + kg];
            #pragma unroll
            for (int j = 0; j < 2; j++)
                wf[j] = *(const short8*)&Pt[(wc*32 + j*16 + fr)*LDT + ks*32 + kg];
            #pragma unroll
            for (int i = 0; i < 2; i++)
                #pragma unroll
                for (int j = 0; j < 2; j++)
                    gacc[i][j] = __builtin_amdgcn_mfma_f32_16x16x32_bf16(af[i], wf[j], gacc[i][j], 0, 0, 0);
        }
        // mask + decay -> Gt (bf16)
        #pragma unroll
        for (int i = 0; i < 2; i++)
            #pragma unroll
            for (int j = 0; j < 2; j++)
                #pragma unroll
                for (int r = 0; r < 4; r++) {
                    int ll = wr*32 + i*16 + rg + r;
                    int ss = wc*32 + j*16 + fr;
                    bool valid = (st < lt) || (ll >= ss);
                    float g = valid ? gacc[i][j][r] * __expf(aL[ll] - aS[ss]) : 0.f;
                    Gt[ll * LDT + ss] = f2s(g);
                }
        __syncthreads();
        // Y += G~ @ X
        #pragma unroll
        for (int ks = 0; ks < 2; ks++) {
            short8 af[2], wf[2];
            #pragma unroll
            for (int i = 0; i < 2; i++)
                af[i] = *(const short8*)&Gt[(wr*32 + i*16 + fr)*LDT + ks*32 + kg];
            #pragma unroll
            for (int j = 0; j < 2; j++)
                wf[j] = *(const short8*)&Xt[(wc*32 + j*16 + fr)*LDT + ks*32 + kg];
            #pragma unroll
            for (int i = 0; i < 2; i++)
                #pragma unroll
                for (int j = 0; j < 2; j++)
                    acc[i][j] = __builtin_amdgcn_mfma_f32_16x16x32_bf16(af[i], wf[j], acc[i][j], 0, 0, 0);
        }
    }

    // fused roll/flip/add epilogue
    #pragma unroll
    for (int i = 0; i < 2; i++)
        #pragma unroll
        for (int r = 0; r < 4; r++) {
            int l = wr*32 + i*16 + rg + r;
            int t = c * CH_ + lt * 64 + l;
            #pragma unroll
            for (int j = 0; j < 2; j++) {
                int p = wc*32 + j*16 + fr;
                float v = acc[i][j][r];
                if (!pass) {
                    int pos = t + 1;
                    if (pos == L_)
                        yc[((size_t)(b * L_)) * DI_ + h * HD_ + p] = f2b(0.f);
                    else
                        yc[((size_t)(b * L_) + pos) * DI_ + h * HD_ + p] = f2b(v);
                } else {
                    int pos = L_ - 2 - t;
                    if (pos >= 0) {
                        size_t o = ((size_t)(b * L_) + pos) * DI_ + h * HD_ + p;
                        yc[o] = f2b(b2f(yc[o]) + v);
                    }
                }
            }
        }
}

// ------------------------------------------------------------------
// combine: D-term GEMV, silu(z) gate, RMSNorm
// ------------------------------------------------------------------
__global__ __launch_bounds__(256) void combine_kernel(const bf16* __restrict__ yc,
                                                      const bf16* __restrict__ conv,
                                                      const bf16* __restrict__ zbuf,
                                                      const float* __restrict__ fcD,
                                                      const float* __restrict__ Dvec,
                                                      const float* __restrict__ rms_w,
                                                      bf16* __restrict__ ybuf) {
    int row = blockIdx.x;
    int tid = threadIdx.x;
    __shared__ float xog_s[DI_];
    __shared__ float dterm_s[NH_];
    __shared__ float rs[4];
    __shared__ float scale_s;
    float yv[6], xog[6], zv[6];
    const bf16* convrow = conv + (size_t)row * CD_;
    const bf16* zrow = zbuf + (size_t)row * DI_;
    const bf16* ycrow = yc + (size_t)row * DI_;
    #pragma unroll
    for (int k = 0; k < 6; k++) {
        int d = tid + k * 256;
        float xo = b2f(convrow[d]);
        xog[k] = xo; xog_s[d] = xo;
        zv[k] = b2f(zrow[d]);
        yv[k] = b2f(ycrow[d]);
    }
    __syncthreads();
    int wid = tid >> 6, lane = tid & 63;
    for (int hh = 0; hh < 6; hh++) {
        int h = wid * 6 + hh;
        float s = 0.f;
        #pragma unroll
        for (int k = 0; k < 24; k++) {
            int d = lane + k * 64;
            s += xog_s[d] * fcD[(size_t)h * DI_ + d];
        }
        for (int off = 32; off > 0; off >>= 1) s += __shfl_down(s, off);
        if (!lane) dterm_s[h] = s + Dvec[h];
    }
    __syncthreads();
    float ss = 0.f;
    #pragma unroll
    for (int k = 0; k < 6; k++) {
        int d = tid + k * 256;
        int h = d >> 6;
        float y = yv[k] + xog[k] * dterm_s[h];
        float z = zv[k];
        y *= z / (1.f + __expf(-z));
        yv[k] = y;
        ss += y * y;
    }
    for (int off = 32; off > 0; off >>= 1) ss += __shfl_down(ss, off);
    if (!lane) rs[wid] = ss;
    __syncthreads();
    if (!tid) scale_s = rsqrtf((rs[0]+rs[1]+rs[2]+rs[3]) / (float)DI_ + EPS_);
    __syncthreads();
    float sc = scale_s;
    bf16* yrow = ybuf + (size_t)row * DI_;
    #pragma unroll
    for (int k = 0; k < 6; k++) {
        int d = tid + k * 256;
        yrow[d] = f2b(yv[k] * sc * rms_w[d]);
    }
}

// ------------------------------------------------------------------
extern "C" void kernel_launch(void* const* d_in, const int* in_sizes, int n_in,
                              void* d_out, int out_size, void* d_ws, size_t ws_size,
                              hipStream_t stream) {
    const float* x        = (const float*)d_in[0];
    const float* ln_w     = (const float*)d_in[1];
    const float* ln_b     = (const float*)d_in[2];
    const float* in_proj  = (const float*)d_in[3];
    const float* conv_w   = (const float*)d_in[4];
    const float* conv_b   = (const float*)d_in[5];
    const float* dt_bias  = (const float*)d_in[6];
    const float* A_log    = (const float*)d_in[7];
    const float* Dvec     = (const float*)d_in[8];
    const float* fc_D_w   = (const float*)d_in[9];
    const float* rms_w    = (const float*)d_in[10];
    const float* out_proj = (const float*)d_in[11];
    float* out = (float*)d_out;

    // ---- workspace layout (lifetime-aliased), ~117 MB ----
    uint8_t* base = (uint8_t*)d_ws;
    size_t off = 0;
    auto alloc = [&](size_t bytes) -> void* {
        void* p = base + off;
        off += (bytes + 255) & ~(size_t)255;
        return p;
    };
    bf16*  buf_z    = (bf16*) alloc((size_t)ROWS_ * DI_ * 2);
    uint8_t* regA   = (uint8_t*)alloc((size_t)ROWS_ * CD_ * 2);
    float* buf_dtr  = (float*)alloc((size_t)ROWS_ * 48 * 4);
    bf16*  buf_conv = (bf16*) alloc((size_t)ROWS_ * CD_ * 2);
    float* buf_dt   = (float*)alloc((size_t)BB4_ * L_ * NH_ * 4);
    float* buf_acum = (float*)alloc((size_t)BB4_ * NH_ * NC_ * CH_ * 4);
    uint8_t* regB   = (uint8_t*)alloc((size_t)ROWS_ * DM_ * 4);
    bf16*  w_in_bf  = (bf16*) alloc((size_t)DIP_ * DM_ * 2);
    bf16*  w_out_bf = (bf16*) alloc((size_t)DM_ * DI_ * 2);

    bf16*  buf_xbc  = (bf16*)regA;
    bf16*  buf_st   = (bf16*)regA;
    bf16*  buf_prev = buf_st + (size_t)BB4_ * NC_ * NH_ * 4096;
    bf16*  buf_y    = (bf16*)regA;
    bf16*  buf_u    = (bf16*)regB;
    bf16*  buf_yc   = (bf16*)regB;

    cast_f2b<<<(DIP_ * DM_ / 4 + 255) / 256, 256, 0, stream>>>(in_proj, w_in_bf, DIP_ * DM_);
    cast_f2b<<<(DM_ * DI_ / 4 + 255) / 256, 256, 0, stream>>>(out_proj, w_out_bf, DM_ * DI_);
    ln_kernel<<<ROWS_, 256, 0, stream>>>(x, ln_w, ln_b, buf_u);
    gemm_bf16_inproj<<<dim3((DIP_ + 127) / 128, ROWS_ / 128), 256, 0, stream>>>(
        buf_u, w_in_bf, buf_z, buf_xbc, buf_dtr);
    {
        size_t tot = (size_t)ROWS_ * CD_;
        conv_kernel<<<(tot + 255) / 256, 256, 0, stream>>>(buf_xbc, conv_w, conv_b, buf_conv);
    }
    dt_kernel<<<(BB4_ * L_ * NH_) / 256, 256, 0, stream>>>(buf_dtr, dt_bias, buf_dt);
    scan_kernel<<<BB4_ * NH_ * NC_, 256, 0, stream>>>(buf_dt, A_log, buf_acum);
    states_kernel<<<BB4_ * NC_ * NH_, 256, 0, stream>>>(buf_conv, buf_dt, buf_acum, buf_st);
    chunkscan_kernel<<<BB4_ * NH_, 256, 0, stream>>>(buf_st, buf_acum, buf_prev);
    ydiag_kernel<<<B_ * NC_ * NH_ * 4, 256, 0, stream>>>(buf_conv, buf_dt, buf_acum, buf_prev, buf_yc, 0);
    ydiag_kernel<<<B_ * NC_ * NH_ * 4, 256, 0, stream>>>(buf_conv, buf_dt, buf_acum, buf_prev, buf_yc, 1);
    combine_kernel<<<ROWS_, 256, 0, stream>>>(buf_yc, buf_conv, buf_z, fc_D_w, Dvec, rms_w, buf_y);
    gemm_bf16_out<<<dim3(DM_ / 128, ROWS_ / 128), 256, 0, stream>>>(
        buf_y, w_out_bf, x, out);
}

// Round 6
// 532.595 us; speedup vs baseline: 3.5205x; 1.0281x over previous
//
#include <hip/hip_runtime.h>
#include <hip/hip_bf16.h>
#include <cstdint>
#include <cstddef>

typedef __hip_bfloat16 bf16;
typedef __attribute__((ext_vector_type(8))) short short8;
typedef __attribute__((ext_vector_type(4))) float f32x4;

// ---- problem constants ----
#define B_   2
#define L_   4096
#define DM_  768      // d_model
#define DI_  1536     // d_inner
#define NH_  24       // nheads
#define HD_  64       // headdim
#define DS_  64       // d_state
#define CH_  256      // chunk
#define NC_  16       // n chunks
#define CD_  1664     // conv dim
#define DIP_ 3248     // d_in_proj
#define EPS_ 1e-5f

#define ROWS_ (B_*L_)        // 8192
#define BB4_  (2*B_)         // 4 ssd batches

#define LDSK 40              // GEMM LDS row stride (shorts)
#define LDT  72              // Gt LDS row stride (shorts)

__device__ __forceinline__ float b2f(bf16 v) { return __bfloat162float(v); }
__device__ __forceinline__ bf16  f2b(float v) { return __float2bfloat16(v); }
__device__ __forceinline__ float sb2f(short s) {
    bf16 t; __builtin_memcpy(&t, &s, 2); return __bfloat162float(t);
}
__device__ __forceinline__ short f2s(float v) {
    bf16 t = __float2bfloat16(v); short s; __builtin_memcpy(&s, &t, 2); return s;
}

// ------------------------------------------------------------------
// cast f32 -> bf16 (weights)
// ------------------------------------------------------------------
__global__ __launch_bounds__(256) void cast_f2b(const float* __restrict__ s,
                                                bf16* __restrict__ d, int n) {
    int i = (blockIdx.x * 256 + threadIdx.x) * 4;
    if (i + 3 < n) {
        float4 v = *(const float4*)(s + i);
        d[i]   = f2b(v.x); d[i+1] = f2b(v.y);
        d[i+2] = f2b(v.z); d[i+3] = f2b(v.w);
    } else {
        for (int k = i; k < n; k++) d[k] = f2b(s[k]);
    }
}

// ------------------------------------------------------------------
// LayerNorm: one block per row (768), bf16 out
// ------------------------------------------------------------------
__global__ __launch_bounds__(256) void ln_kernel(const float* __restrict__ x,
                                                 const float* __restrict__ w,
                                                 const float* __restrict__ bb,
                                                 bf16* __restrict__ u) {
    int row = blockIdx.x, tid = threadIdx.x;
    const float* xr = x + (size_t)row * DM_;
    float v0 = xr[tid], v1 = xr[tid + 256], v2 = xr[tid + 512];
    float s = v0 + v1 + v2;
    float q = v0*v0 + v1*v1 + v2*v2;
    for (int off = 32; off > 0; off >>= 1) {
        s += __shfl_down(s, off);
        q += __shfl_down(q, off);
    }
    __shared__ float rs[4], rq[4];
    __shared__ float mean_s, rstd_s;
    int lane = tid & 63, wid = tid >> 6;
    if (!lane) { rs[wid] = s; rq[wid] = q; }
    __syncthreads();
    if (!tid) {
        float S = rs[0]+rs[1]+rs[2]+rs[3];
        float Q = rq[0]+rq[1]+rq[2]+rq[3];
        float mu = S / (float)DM_;
        float var = Q / (float)DM_ - mu*mu;
        mean_s = mu; rstd_s = rsqrtf(var + EPS_);
    }
    __syncthreads();
    float mu = mean_s, rstd = rstd_s;
    bf16* ur = u + (size_t)row * DM_;
    ur[tid]       = f2b((v0 - mu) * rstd * w[tid]       + bb[tid]);
    ur[tid + 256] = f2b((v1 - mu) * rstd * w[tid + 256] + bb[tid + 256]);
    ur[tid + 512] = f2b((v2 - mu) * rstd * w[tid + 512] + bb[tid + 512]);
}

// ------------------------------------------------------------------
// MFMA bf16 GEMM (in_proj): C[8192,3248] = u @ W^T, split epilogue
// ------------------------------------------------------------------
__global__ __launch_bounds__(256) void gemm_bf16_inproj(const bf16* __restrict__ A,
                                                        const bf16* __restrict__ W,
                                                        bf16* __restrict__ zbuf,
                                                        bf16* __restrict__ xbc,
                                                        float* __restrict__ dtr) {
    __shared__ short As[128 * LDSK];
    __shared__ short Ws[128 * LDSK];
    int tid = threadIdx.x;
    int wave = tid >> 6, lane = tid & 63;
    int wm = (wave >> 1) * 64, wn = (wave & 1) * 64;
    int bm = blockIdx.y * 128, bn = blockIdx.x * 128;
    f32x4 acc[4][4] = {};
    int lr = tid >> 1;
    int lseg = (tid & 1) * 16;
    const int K = DM_;
    int fr = lane & 15, kg = (lane >> 4) * 8;
    for (int k0 = 0; k0 < K; k0 += 32) {
        const short* ag = (const short*)A + (size_t)(bm + lr) * K + k0 + lseg;
        short8 av0 = *(const short8*)ag;
        short8 av1 = *(const short8*)(ag + 8);
        short8 wv0 = {}, wv1 = {};
        int n = bn + lr;
        if (n < DIP_) {
            const short* wg = (const short*)W + (size_t)n * K + k0 + lseg;
            wv0 = *(const short8*)wg;
            wv1 = *(const short8*)(wg + 8);
        }
        __syncthreads();
        *(short8*)&As[lr*LDSK + lseg]     = av0;
        *(short8*)&As[lr*LDSK + lseg + 8] = av1;
        *(short8*)&Ws[lr*LDSK + lseg]     = wv0;
        *(short8*)&Ws[lr*LDSK + lseg + 8] = wv1;
        __syncthreads();
        short8 af[4], wf[4];
        #pragma unroll
        for (int i = 0; i < 4; i++)
            af[i] = *(const short8*)&As[(wm + i*16 + fr)*LDSK + kg];
        #pragma unroll
        for (int j = 0; j < 4; j++)
            wf[j] = *(const short8*)&Ws[(wn + j*16 + fr)*LDSK + kg];
        #pragma unroll
        for (int i = 0; i < 4; i++)
            #pragma unroll
            for (int j = 0; j < 4; j++)
                acc[i][j] = __builtin_amdgcn_mfma_f32_16x16x32_bf16(af[i], wf[j], acc[i][j], 0, 0, 0);
    }
    int rg = (lane >> 4) * 4;
    #pragma unroll
    for (int i = 0; i < 4; i++) {
        int mrow = bm + wm + i*16 + rg;
        #pragma unroll
        for (int j = 0; j < 4; j++) {
            int ncol = bn + wn + j*16 + fr;
            #pragma unroll
            for (int r = 0; r < 4; r++) {
                float v = acc[i][j][r];
                int m = mrow + r;
                if (ncol < DI_)            zbuf[(size_t)m * DI_ + ncol] = f2b(v);
                else if (ncol < DI_ + CD_) xbc[(size_t)m * CD_ + (ncol - DI_)] = f2b(v);
                else if (ncol < DIP_)      dtr[(size_t)m * 48 + (ncol - DI_ - CD_)] = v;
            }
        }
    }
}

// ------------------------------------------------------------------
// MFMA bf16 GEMM (out_proj): out = y @ W^T + x
// ------------------------------------------------------------------
__global__ __launch_bounds__(256) void gemm_bf16_out(const bf16* __restrict__ A,
                                                     const bf16* __restrict__ W,
                                                     const float* __restrict__ resid,
                                                     float* __restrict__ C) {
    __shared__ short As[128 * LDSK];
    __shared__ short Ws[128 * LDSK];
    int tid = threadIdx.x;
    int wave = tid >> 6, lane = tid & 63;
    int wm = (wave >> 1) * 64, wn = (wave & 1) * 64;
    int bm = blockIdx.y * 128, bn = blockIdx.x * 128;
    f32x4 acc[4][4] = {};
    int lr = tid >> 1;
    int lseg = (tid & 1) * 16;
    const int K = DI_;
    int fr = lane & 15, kg = (lane >> 4) * 8;
    for (int k0 = 0; k0 < K; k0 += 32) {
        const short* ag = (const short*)A + (size_t)(bm + lr) * K + k0 + lseg;
        short8 av0 = *(const short8*)ag;
        short8 av1 = *(const short8*)(ag + 8);
        const short* wg = (const short*)W + (size_t)(bn + lr) * K + k0 + lseg;
        short8 wv0 = *(const short8*)wg;
        short8 wv1 = *(const short8*)(wg + 8);
        __syncthreads();
        *(short8*)&As[lr*LDSK + lseg]     = av0;
        *(short8*)&As[lr*LDSK + lseg + 8] = av1;
        *(short8*)&Ws[lr*LDSK + lseg]     = wv0;
        *(short8*)&Ws[lr*LDSK + lseg + 8] = wv1;
        __syncthreads();
        short8 af[4], wf[4];
        #pragma unroll
        for (int i = 0; i < 4; i++)
            af[i] = *(const short8*)&As[(wm + i*16 + fr)*LDSK + kg];
        #pragma unroll
        for (int j = 0; j < 4; j++)
            wf[j] = *(const short8*)&Ws[(wn + j*16 + fr)*LDSK + kg];
        #pragma unroll
        for (int i = 0; i < 4; i++)
            #pragma unroll
            for (int j = 0; j < 4; j++)
                acc[i][j] = __builtin_amdgcn_mfma_f32_16x16x32_bf16(af[i], wf[j], acc[i][j], 0, 0, 0);
    }
    int rg = (lane >> 4) * 4;
    #pragma unroll
    for (int i = 0; i < 4; i++) {
        int mrow = bm + wm + i*16 + rg;
        #pragma unroll
        for (int j = 0; j < 4; j++) {
            int ncol = bn + wn + j*16 + fr;
            #pragma unroll
            for (int r = 0; r < 4; r++) {
                int m = mrow + r;
                C[(size_t)m * DM_ + ncol] = acc[i][j][r] + resid[(size_t)m * DM_ + ncol];
            }
        }
    }
}

// ------------------------------------------------------------------
// Depthwise causal conv7 + SiLU, vectorized: 8 channels x 4 t per thread
// ------------------------------------------------------------------
__global__ __launch_bounds__(256) void conv_kernel(const bf16* __restrict__ xbc,
                                                   const float* __restrict__ cw,
                                                   const float* __restrict__ cb,
                                                   bf16* __restrict__ out) {
    int g = blockIdx.x * 256 + threadIdx.x;   // 425,984 total
    int cg = g % 208;                          // channel-group (8 ch)
    int tq = g / 208;                          // b*1024 + t0/4
    int b = tq >> 10;
    int t0 = (tq & 1023) * 4;
    int c8 = cg * 8;
    const short* src = (const short*)xbc + (size_t)(b * L_) * CD_ + c8;

    float w[7][8], acc[4][8];
    #pragma unroll
    for (int k = 0; k < 8; k++) {
        #pragma unroll
        for (int j = 0; j < 7; j++) w[j][k] = cw[(c8 + k) * 7 + j];
        float bias = cb[c8 + k];
        #pragma unroll
        for (int q = 0; q < 4; q++) acc[q][k] = bias;
    }
    #pragma unroll
    for (int m = 0; m < 10; m++) {
        int tt = t0 - 6 + m;
        float row[8];
        if (tt >= 0) {
            short8 v = *(const short8*)(src + (size_t)tt * CD_);
            #pragma unroll
            for (int k = 0; k < 8; k++) row[k] = sb2f(v[k]);
        } else {
            #pragma unroll
            for (int k = 0; k < 8; k++) row[k] = 0.f;
        }
        #pragma unroll
        for (int q = 0; q < 4; q++) {
            int j = m - q;
            if (j >= 0 && j < 7) {
                #pragma unroll
                for (int k = 0; k < 8; k++) acc[q][k] += row[k] * w[j][k];
            }
        }
    }
    #pragma unroll
    for (int q = 0; q < 4; q++) {
        short8 o;
        #pragma unroll
        for (int k = 0; k < 8; k++) {
            float a = acc[q][k];
            a = a / (1.f + __expf(-a));
            o[k] = f2s(a);
        }
        *(short8*)((short*)out + (size_t)(b * L_ + t0 + q) * CD_ + c8) = o;
    }
}

// ------------------------------------------------------------------
// dt: softplus(dt2 + bias) with flip for bwd batches
// ------------------------------------------------------------------
__global__ __launch_bounds__(256) void dt_kernel(const float* __restrict__ dtr,
                                                 const float* __restrict__ dt_bias,
                                                 float* __restrict__ dt4) {
    int idx = blockIdx.x * 256 + threadIdx.x;
    if (idx >= BB4_ * L_ * NH_) return;
    int h = idx % NH_;
    int t = (idx / NH_) % L_;
    int bbx = idx / (NH_ * L_);
    int bp = bbx & 1;
    float raw;
    if (bbx < 2) raw = dtr[((size_t)(bp * L_ + t)) * 48 + h];
    else         raw = dtr[((size_t)(bp * L_ + (L_ - 1 - t))) * 48 + NH_ + h];
    float v = raw + dt_bias[h];
    float dt = (v > 20.f) ? v : log1pf(__expf(v));
    dt4[idx] = dt;
}

// ------------------------------------------------------------------
// per-chunk inclusive cumsum of dt*A
// ------------------------------------------------------------------
__global__ __launch_bounds__(256) void scan_kernel(const float* __restrict__ dt4,
                                                   const float* __restrict__ A_log,
                                                   float* __restrict__ Acum) {
    int bid = blockIdx.x;          // ((bb*NH+h)*NC+c)
    int c  = bid % NC_;
    int h  = (bid / NC_) % NH_;
    int bbx = bid / (NC_ * NH_);
    int l = threadIdx.x;
    float Ah = -__expf(A_log[h]);
    float val = dt4[((size_t)(bbx * L_) + c * CH_ + l) * NH_ + h] * Ah;
    __shared__ float sc[256];
    sc[l] = val; __syncthreads();
    for (int off = 1; off < 256; off <<= 1) {
        float t = (l >= off) ? sc[l - off] : 0.f;
        __syncthreads();
        sc[l] += t;
        __syncthreads();
    }
    Acum[(size_t)bid * CH_ + l] = sc[l];
}

// ------------------------------------------------------------------
// pre-transpose: XT[bbx,h][p][t] = conv_x[tt][h*64+p] * dt4[bbx][t]
//                BT[bbx][n][t]   = conv_B[tt][n]
// grid: (bbx*NC + c)*25 + hh   (hh==24 -> BT)
// ------------------------------------------------------------------
__global__ __launch_bounds__(256) void xt_kernel(const bf16* __restrict__ conv,
                                                 const float* __restrict__ dt4,
                                                 bf16* __restrict__ XT,
                                                 bf16* __restrict__ BT) {
    int bid = blockIdx.x;
    int hh = bid % 25;
    int c  = (bid / 25) % NC_;
    int bbx = bid / (25 * NC_);
    int bp = bbx & 1;
    bool flip = bbx >= 2;
    bool isB = (hh == NH_);
    int coff = isB ? DI_ : hh * HD_;
    int tid = threadIdx.x;
    __shared__ short tile[64][72];
    short* dstb = (short*)(isB ? BT : XT);
    size_t rowbase = isB ? (size_t)(bbx * 64) : (size_t)((bbx * NH_ + hh) * 64);
    for (int lt = 0; lt < 4; lt++) {
        __syncthreads();
        #pragma unroll
        for (int it = 0; it < 2; it++) {
            int li = tid + it * 256;
            int r = li >> 3, seg = (li & 7) * 8;
            int t = c * CH_ + lt * 64 + r;
            int tt = flip ? (L_ - 1 - t) : t;
            short8 v = *(const short8*)((const short*)conv + (size_t)(bp * L_ + tt) * CD_ + coff + seg);
            if (!isB) {
                float dtv = dt4[((size_t)(bbx * L_) + t) * NH_ + hh];
                #pragma unroll
                for (int k = 0; k < 8; k++) v[k] = f2s(sb2f(v[k]) * dtv);
            }
            *(short8*)&tile[r][seg] = v;
        }
        __syncthreads();
        #pragma unroll
        for (int it = 0; it < 2; it++) {
            int li = tid + it * 256;
            int p = li >> 3, seg = (li & 7) * 8;
            short8 o;
            #pragma unroll
            for (int k = 0; k < 8; k++) o[k] = tile[seg + k][p];
            *(short8*)(dstb + (rowbase + p) * L_ + c * CH_ + lt * 64 + seg) = o;
        }
    }
}

// ------------------------------------------------------------------
// chunk states (MFMA, direct-load): S^T[p][n] = sum_l XT[p][l]*BT[n][l]*dec[l]
// ------------------------------------------------------------------
__global__ __launch_bounds__(256) void states_kernel(const bf16* __restrict__ XT,
                                                     const bf16* __restrict__ BT,
                                                     const float* __restrict__ Acum,
                                                     bf16* __restrict__ states) {
    int bid = blockIdx.x;          // (bbx*NC+c)*NH + h
    int h = bid % NH_;
    int c = (bid / NH_) % NC_;
    int bbx = bid / (NH_ * NC_);
    int tid = threadIdx.x;
    int wave = tid >> 6, lane = tid & 63;
    int wr = wave >> 1, wc = wave & 1;
    int fr = lane & 15, kg = (lane >> 4) * 8, rg = (lane >> 4) * 4;
    size_t abase = ((size_t)(bbx * NH_ + h) * NC_ + c) * CH_;
    __shared__ float dec[256];
    {
        float Atot = Acum[abase + CH_ - 1];
        dec[tid] = __expf(Atot - Acum[abase + tid]);
    }
    __syncthreads();
    const short* xbase = (const short*)XT + (size_t)((bbx * NH_ + h) * 64) * L_ + c * CH_;
    const short* bbase = (const short*)BT + (size_t)(bbx * 64) * L_ + c * CH_;
    f32x4 acc[2][2] = {};
    for (int lt = 0; lt < 4; lt++) {
        #pragma unroll
        for (int ks = 0; ks < 2; ks++) {
            int l0 = lt * 64 + ks * 32 + kg;
            float d[8];
            #pragma unroll
            for (int k = 0; k < 8; k++) d[k] = dec[l0 + k];
            short8 af[2], wf[2];
            #pragma unroll
            for (int i = 0; i < 2; i++)
                af[i] = *(const short8*)(xbase + (size_t)(wr*32 + i*16 + fr) * L_ + l0);
            #pragma unroll
            for (int j = 0; j < 2; j++) {
                short8 raw = *(const short8*)(bbase + (size_t)(wc*32 + j*16 + fr) * L_ + l0);
                #pragma unroll
                for (int k = 0; k < 8; k++) raw[k] = f2s(sb2f(raw[k]) * d[k]);
                wf[j] = raw;
            }
            #pragma unroll
            for (int i = 0; i < 2; i++)
                #pragma unroll
                for (int j = 0; j < 2; j++)
                    acc[i][j] = __builtin_amdgcn_mfma_f32_16x16x32_bf16(af[i], wf[j], acc[i][j], 0, 0, 0);
        }
    }
    size_t sbase = (size_t)bid * 4096;
    #pragma unroll
    for (int i = 0; i < 2; i++)
        #pragma unroll
        for (int j = 0; j < 2; j++)
            #pragma unroll
            for (int r = 0; r < 4; r++) {
                int p = wr*32 + i*16 + rg + r;
                int n = wc*32 + j*16 + fr;
                states[sbase + p*64 + n] = f2b(acc[i][j][r]);
            }
}

// ------------------------------------------------------------------
// inter-chunk recurrence, IN-PLACE: buf[c] <- running prev, run += state[c]
// ------------------------------------------------------------------
__global__ __launch_bounds__(256) void chunkscan_kernel(bf16* __restrict__ sp,
                                                        const float* __restrict__ Acum) {
    int bid = blockIdx.x;  // bb*NH + h
    int h = bid % NH_;
    int bbx = bid / NH_;
    int tid = threadIdx.x;
    float run[16];
    #pragma unroll
    for (int k = 0; k < 16; k++) run[k] = 0.f;
    for (int c = 0; c < NC_; c++) {
        float Tc = Acum[((size_t)(bbx * NH_ + h) * NC_ + c) * CH_ + CH_ - 1];
        float ec = __expf(Tc);
        size_t base = ((size_t)(bbx * NC_ + c) * NH_ + h) * 4096;
        #pragma unroll
        for (int k = 0; k < 16; k++) {
            size_t e = tid + k * 256;
            float sv = b2f(sp[base + e]);
            sp[base + e] = f2b(run[k]);
            run[k] = run[k] * ec + sv;
        }
    }
}

// ------------------------------------------------------------------
// Y = Y_diag + Y_off (MFMA, direct-load) per (b,c,h,lt)
// pass 0: yc[b, t+1] = y (t==L-1 -> zero row 0)
// pass 1: yc[b, L-2-t] += y (t==L-1 dropped)
// ------------------------------------------------------------------
__global__ __launch_bounds__(256) void ydiag_kernel(const bf16* __restrict__ conv,
                                                    const bf16* __restrict__ XT,
                                                    const float* __restrict__ Acum,
                                                    const bf16* __restrict__ prev,
                                                    bf16* __restrict__ yc,
                                                    int pass) {
    int bid = blockIdx.x;   // ((b*NC+c)*NH+h)*4 + lt
    int lt = bid & 3;
    int q  = bid >> 2;
    int h  = q % NH_;
    int r2 = q / NH_;
    int c  = r2 % NC_;
    int b  = r2 / NC_;
    int bbx = pass ? (b + 2) : b;
    int bp = b;
    bool flip = pass != 0;
    int tid = threadIdx.x;
    int wave = tid >> 6, lane = tid & 63;
    int wr = wave >> 1, wc = wave & 1;
    int fr = lane & 15, kg = (lane >> 4) * 8, rg = (lane >> 4) * 4;
    size_t abase = ((size_t)(bbx * NH_ + h) * NC_ + c) * CH_;

    __shared__ short Gt[64 * LDT];
    __shared__ float aL[64], aS[64];
    if (tid < 64) aL[tid] = Acum[abase + lt * 64 + tid];

    // C fragments, held in registers for the whole kernel
    short8 cf[2][2];
    #pragma unroll
    for (int i = 0; i < 2; i++) {
        int l = wr*32 + i*16 + fr;
        int t = c * CH_ + lt * 64 + l;
        int tt = flip ? (L_ - 1 - t) : t;
        const short* crow = (const short*)conv + (size_t)(bp * L_ + tt) * CD_ + DI_ + DS_;
        #pragma unroll
        for (int ks = 0; ks < 2; ks++)
            cf[i][ks] = *(const short8*)(crow + ks*32 + kg);
    }

    // Y_off = (C @ prevT) then * exp(aL[row])
    f32x4 acc[2][2] = {};
    size_t pbase = ((size_t)(bbx * NC_ + c) * NH_ + h) * 4096;
    #pragma unroll
    for (int ks = 0; ks < 2; ks++) {
        #pragma unroll
        for (int j = 0; j < 2; j++) {
            short8 pf = *(const short8*)((const short*)prev + pbase + (size_t)(wc*32 + j*16 + fr)*64 + ks*32 + kg);
            #pragma unroll
            for (int i = 0; i < 2; i++)
                acc[i][j] = __builtin_amdgcn_mfma_f32_16x16x32_bf16(cf[i][ks], pf, acc[i][j], 0, 0, 0);
        }
    }
    __syncthreads();   // aL visible
    #pragma unroll
    for (int i = 0; i < 2; i++)
        #pragma unroll
        for (int r = 0; r < 4; r++) {
            float e = __expf(aL[wr*32 + i*16 + rg + r]);
            #pragma unroll
            for (int j = 0; j < 2; j++) acc[i][j][r] *= e;
        }

    const short* xbase = (const short*)XT + (size_t)((bbx * NH_ + h) * 64) * L_ + c * CH_;

    for (int st = 0; st <= lt; st++) {
        if (tid < 64) aS[tid] = Acum[abase + st * 64 + tid];
        // G = C @ B^T  (B direct from conv)
        f32x4 gacc[2][2] = {};
        #pragma unroll
        for (int j = 0; j < 2; j++) {
            int s = wc*32 + j*16 + fr;
            int t = c * CH_ + st * 64 + s;
            int tt = flip ? (L_ - 1 - t) : t;
            const short* brow = (const short*)conv + (size_t)(bp * L_ + tt) * CD_ + DI_;
            #pragma unroll
            for (int ks = 0; ks < 2; ks++) {
                short8 bf = *(const short8*)(brow + ks*32 + kg);
                #pragma unroll
                for (int i = 0; i < 2; i++)
                    gacc[i][j] = __builtin_amdgcn_mfma_f32_16x16x32_bf16(cf[i][ks], bf, gacc[i][j], 0, 0, 0);
            }
        }
        __syncthreads();  // aS visible; prior Gt reads complete
        #pragma unroll
        for (int i = 0; i < 2; i++)
            #pragma unroll
            for (int j = 0; j < 2; j++)
                #pragma unroll
                for (int r = 0; r < 4; r++) {
                    int ll = wr*32 + i*16 + rg + r;
                    int ss = wc*32 + j*16 + fr;
                    bool valid = (st < lt) || (ll >= ss);
                    float g = valid ? gacc[i][j][r] * __expf(aL[ll] - aS[ss]) : 0.f;
                    Gt[ll * LDT + ss] = f2s(g);
                }
        __syncthreads();
        // Y += G~ @ X  (X direct from XT)
        #pragma unroll
        for (int ks = 0; ks < 2; ks++) {
            short8 gf[2], xf[2];
            #pragma unroll
            for (int i = 0; i < 2; i++)
                gf[i] = *(const short8*)&Gt[(wr*32 + i*16 + fr)*LDT + ks*32 + kg];
            #pragma unroll
            for (int j = 0; j < 2; j++)
                xf[j] = *(const short8*)(xbase + (size_t)(wc*32 + j*16 + fr)*L_ + st*64 + ks*32 + kg);
            #pragma unroll
            for (int i = 0; i < 2; i++)
                #pragma unroll
                for (int j = 0; j < 2; j++)
                    acc[i][j] = __builtin_amdgcn_mfma_f32_16x16x32_bf16(gf[i], xf[j], acc[i][j], 0, 0, 0);
        }
        __syncthreads();  // Gt reads done before next overwrite
    }

    // fused roll/flip/add epilogue
    #pragma unroll
    for (int i = 0; i < 2; i++)
        #pragma unroll
        for (int r = 0; r < 4; r++) {
            int l = wr*32 + i*16 + rg + r;
            int t = c * CH_ + lt * 64 + l;
            #pragma unroll
            for (int j = 0; j < 2; j++) {
                int p = wc*32 + j*16 + fr;
                float v = acc[i][j][r];
                if (!pass) {
                    int pos = t + 1;
                    if (pos == L_)
                        yc[((size_t)(b * L_)) * DI_ + h * HD_ + p] = f2b(0.f);
                    else
                        yc[((size_t)(b * L_) + pos) * DI_ + h * HD_ + p] = f2b(v);
                } else {
                    int pos = L_ - 2 - t;
                    if (pos >= 0) {
                        size_t o = ((size_t)(b * L_) + pos) * DI_ + h * HD_ + p;
                        yc[o] = f2b(b2f(yc[o]) + v);
                    }
                }
            }
        }
}

// ------------------------------------------------------------------
// combine: D-term GEMV, silu(z) gate, RMSNorm
// ------------------------------------------------------------------
__global__ __launch_bounds__(256) void combine_kernel(const bf16* __restrict__ yc,
                                                      const bf16* __restrict__ conv,
                                                      const bf16* __restrict__ zbuf,
                                                      const float* __restrict__ fcD,
                                                      const float* __restrict__ Dvec,
                                                      const float* __restrict__ rms_w,
                                                      bf16* __restrict__ ybuf) {
    int row = blockIdx.x;
    int tid = threadIdx.x;
    __shared__ float xog_s[DI_];
    __shared__ float dterm_s[NH_];
    __shared__ float rs[4];
    __shared__ float scale_s;
    float yv[6], xog[6], zv[6];
    const bf16* convrow = conv + (size_t)row * CD_;
    const bf16* zrow = zbuf + (size_t)row * DI_;
    const bf16* ycrow = yc + (size_t)row * DI_;
    #pragma unroll
    for (int k = 0; k < 6; k++) {
        int d = tid + k * 256;
        float xo = b2f(convrow[d]);
        xog[k] = xo; xog_s[d] = xo;
        zv[k] = b2f(zrow[d]);
        yv[k] = b2f(ycrow[d]);
    }
    __syncthreads();
    int wid = tid >> 6, lane = tid & 63;
    for (int hh = 0; hh < 6; hh++) {
        int h = wid * 6 + hh;
        float s = 0.f;
        #pragma unroll
        for (int k = 0; k < 24; k++) {
            int d = lane + k * 64;
            s += xog_s[d] * fcD[(size_t)h * DI_ + d];
        }
        for (int off = 32; off > 0; off >>= 1) s += __shfl_down(s, off);
        if (!lane) dterm_s[h] = s + Dvec[h];
    }
    __syncthreads();
    float ss = 0.f;
    #pragma unroll
    for (int k = 0; k < 6; k++) {
        int d = tid + k * 256;
        int h = d >> 6;
        float y = yv[k] + xog[k] * dterm_s[h];
        float z = zv[k];
        y *= z / (1.f + __expf(-z));
        yv[k] = y;
        ss += y * y;
    }
    for (int off = 32; off > 0; off >>= 1) ss += __shfl_down(ss, off);
    if (!lane) rs[wid] = ss;
    __syncthreads();
    if (!tid) scale_s = rsqrtf((rs[0]+rs[1]+rs[2]+rs[3]) / (float)DI_ + EPS_);
    __syncthreads();
    float sc = scale_s;
    bf16* yrow = ybuf + (size_t)row * DI_;
    #pragma unroll
    for (int k = 0; k < 6; k++) {
        int d = tid + k * 256;
        yrow[d] = f2b(yv[k] * sc * rms_w[d]);
    }
}

// ------------------------------------------------------------------
extern "C" void kernel_launch(void* const* d_in, const int* in_sizes, int n_in,
                              void* d_out, int out_size, void* d_ws, size_t ws_size,
                              hipStream_t stream) {
    const float* x        = (const float*)d_in[0];
    const float* ln_w     = (const float*)d_in[1];
    const float* ln_b     = (const float*)d_in[2];
    const float* in_proj  = (const float*)d_in[3];
    const float* conv_w   = (const float*)d_in[4];
    const float* conv_b   = (const float*)d_in[5];
    const float* dt_bias  = (const float*)d_in[6];
    const float* A_log    = (const float*)d_in[7];
    const float* Dvec     = (const float*)d_in[8];
    const float* fc_D_w   = (const float*)d_in[9];
    const float* rms_w    = (const float*)d_in[10];
    const float* out_proj = (const float*)d_in[11];
    float* out = (float*)d_out;

    // ---- workspace layout (lifetime-aliased), ~170 MB ----
    uint8_t* base = (uint8_t*)d_ws;
    size_t off = 0;
    auto alloc = [&](size_t bytes) -> void* {
        void* p = base + off;
        off += (bytes + 255) & ~(size_t)255;
        return p;
    };
    bf16*  buf_z    = (bf16*) alloc((size_t)ROWS_ * DI_ * 2);            // z [2..9]
    uint8_t* regA   = (uint8_t*)alloc((size_t)ROWS_ * CD_ * 2);          // xbc[2..3]/sp[6..8]/y[9..10]
    float* buf_dtr  = (float*)alloc((size_t)ROWS_ * 48 * 4);
    bf16*  buf_conv = (bf16*) alloc((size_t)ROWS_ * CD_ * 2);            // conv [3..9]
    float* buf_dt   = (float*)alloc((size_t)BB4_ * L_ * NH_ * 4);
    float* buf_acum = (float*)alloc((size_t)BB4_ * NH_ * NC_ * CH_ * 4);
    uint8_t* regB   = (uint8_t*)alloc((size_t)ROWS_ * DM_ * 4);          // u[1..2]/yc[8..9]
    bf16*  w_in_bf  = (bf16*) alloc((size_t)DIP_ * DM_ * 2);
    bf16*  w_out_bf = (bf16*) alloc((size_t)DM_ * DI_ * 2);
    bf16*  buf_XT   = (bf16*) alloc((size_t)BB4_ * NH_ * 64 * L_ * 2);   // 50.3 MB [xt..ydiag]
    bf16*  buf_BT   = (bf16*) alloc((size_t)BB4_ * 64 * L_ * 2);         // 2.1 MB

    bf16*  buf_xbc  = (bf16*)regA;
    bf16*  buf_sp   = (bf16*)regA;     // states->prev in place
    bf16*  buf_y    = (bf16*)regA;
    bf16*  buf_u    = (bf16*)regB;
    bf16*  buf_yc   = (bf16*)regB;

    cast_f2b<<<(DIP_ * DM_ / 4 + 255) / 256, 256, 0, stream>>>(in_proj, w_in_bf, DIP_ * DM_);
    cast_f2b<<<(DM_ * DI_ / 4 + 255) / 256, 256, 0, stream>>>(out_proj, w_out_bf, DM_ * DI_);
    ln_kernel<<<ROWS_, 256, 0, stream>>>(x, ln_w, ln_b, buf_u);
    gemm_bf16_inproj<<<dim3((DIP_ + 127) / 128, ROWS_ / 128), 256, 0, stream>>>(
        buf_u, w_in_bf, buf_z, buf_xbc, buf_dtr);
    conv_kernel<<<(ROWS_ / 4) * (CD_ / 8) / 256, 256, 0, stream>>>(buf_xbc, conv_w, conv_b, buf_conv);
    dt_kernel<<<(BB4_ * L_ * NH_) / 256, 256, 0, stream>>>(buf_dtr, dt_bias, buf_dt);
    scan_kernel<<<BB4_ * NH_ * NC_, 256, 0, stream>>>(buf_dt, A_log, buf_acum);
    xt_kernel<<<BB4_ * NC_ * 25, 256, 0, stream>>>(buf_conv, buf_dt, buf_XT, buf_BT);
    states_kernel<<<BB4_ * NC_ * NH_, 256, 0, stream>>>(buf_XT, buf_BT, buf_acum, buf_sp);
    chunkscan_kernel<<<BB4_ * NH_, 256, 0, stream>>>(buf_sp, buf_acum);
    ydiag_kernel<<<B_ * NC_ * NH_ * 4, 256, 0, stream>>>(buf_conv, buf_XT, buf_acum, buf_sp, buf_yc, 0);
    ydiag_kernel<<<B_ * NC_ * NH_ * 4, 256, 0, stream>>>(buf_conv, buf_XT, buf_acum, buf_sp, buf_yc, 1);
    combine_kernel<<<ROWS_, 256, 0, stream>>>(buf_yc, buf_conv, buf_z, fc_D_w, Dvec, rms_w, buf_y);
    gemm_bf16_out<<<dim3(DM_ / 128, ROWS_ / 128), 256, 0, stream>>>(
        buf_y, w_out_bf, x, out);
}